// Round 10
// baseline (351.983 us; speedup 1.0000x reference)
//
#include <hip/hip_runtime.h>
#include <hip/hip_bf16.h>
#include <math.h>

typedef __hip_bfloat16 bf16;
typedef __attribute__((ext_vector_type(8))) short short8;
typedef __attribute__((ext_vector_type(4))) float f32x4;

constexpr int BB    = 2;      // batch
constexpr int LL    = 4096;   // seq len
constexpr int DM    = 1024;   // d_model
constexpr int DIN   = 2048;   // d_inner
constexpr int HH    = 32;     // n_heads
constexpr int PP    = 64;     // head_dim
constexpr int NSD   = 128;    // d_state
constexpr int CONVD = 2304;   // d_inner + 2*d_state
constexpr int DPROJ = 4384;   // 2*d_inner + 2*d_state + n_heads
constexpr int CHK   = 64;     // chunk size
constexpr int NC    = 64;     // chunks per batch (L/CHK)
constexpr int ROWS  = BB * LL; // 8192

// 256-sq 8-phase gemm geometry (in_proj)
constexpr int NPAD2 = 4608;        // DPROJ padded to 18*256
constexpr int GX2   = NPAD2 / 256; // 18
constexpr int GY2   = ROWS / 256;  // 32
constexpr int NWG2  = GX2 * GY2;   // 576 (% 8 == 0)
constexpr int NT2   = DM / 64;     // 16 K-tiles

__device__ __forceinline__ float b2f(bf16 v) { return __bfloat162float(v); }
__device__ __forceinline__ bf16  f2b(float f) { return __float2bfloat16(f); }
__device__ __forceinline__ short f2bs(float f) {
  bf16 b = f2b(f);
  return *reinterpret_cast<short*>(&b);
}
// async global->LDS, 16B per lane; LDS dest = base + lane*16 (wave-uniform base)
__device__ __forceinline__ void gload16(const short* g, short* l) {
  __builtin_amdgcn_global_load_lds(
      (const __attribute__((address_space(1))) void*)g,
      (__attribute__((address_space(3))) void*)l, 16, 0, 0);
}
template <int N> __device__ __forceinline__ void waitvm() {
  if constexpr (N == 0)      asm volatile("s_waitcnt vmcnt(0)" ::: "memory");
  else if constexpr (N == 3) asm volatile("s_waitcnt vmcnt(3)" ::: "memory");
  else                       asm volatile("s_waitcnt vmcnt(4)" ::: "memory");
}
__device__ __forceinline__ void barrier_raw() {
  asm volatile("s_barrier" ::: "memory");
}

// ---------------------------------------------------------------------------
// fp32 -> bf16 elementwise. 4 elems/thread.
// ---------------------------------------------------------------------------
__global__ __launch_bounds__(256) void convert_bf16(const float* __restrict__ in,
                                                    bf16* __restrict__ outp, int n4) {
  int i = blockIdx.x * 256 + threadIdx.x;
  if (i >= n4) return;
  float4 v = *(const float4*)&in[(size_t)i * 4];
  bf16* p = &outp[(size_t)i * 4];
  p[0] = f2b(v.x); p[1] = f2b(v.y); p[2] = f2b(v.z); p[3] = f2b(v.w);
}

// ---------------------------------------------------------------------------
// Transpose + convert: W fp32 [K][N] row-major -> Bt bf16 [Npad][K] row-major.
// ---------------------------------------------------------------------------
__global__ __launch_bounds__(256) void transpose_w(const float* __restrict__ W,
                                                   bf16* __restrict__ Bt,
                                                   int K, int N) {
  __shared__ float Tl[32][33];
  const int n0 = blockIdx.x * 32, k0 = blockIdx.y * 32;
  const int t = threadIdx.x;
  {
    const int kk = t >> 3, nn4 = (t & 7) * 4;
#pragma unroll
    for (int j = 0; j < 4; ++j) {
      int n = n0 + nn4 + j;
      Tl[kk][nn4 + j] = (n < N) ? W[(size_t)(k0 + kk) * N + n] : 0.f;
    }
  }
  __syncthreads();
  {
    const int nn = t >> 3, kk4 = (t & 7) * 4;
#pragma unroll
    for (int j = 0; j < 4; ++j)
      Bt[(size_t)(n0 + nn) * K + k0 + kk4 + j] = f2b(Tl[kk4 + j][nn]);
  }
}

// ---------------------------------------------------------------------------
// 256x256 8-phase bf16 MFMA GEMM (in_proj). 8 waves (2M x 4N), BK=64, 2 dbuf,
// 128 KiB dynamic LDS. Per K-tile: 4 phases, each {ds_read subtile; stage one
// half-tile (2 gload_lds); barrier; setprio(1) 16 MFMA setprio(0); barrier}.
// Staging schedule (race-audited): tile T's A-halves at (T-1).P1/P2 (other
// dbuf), B-halves at (T-2).P3/P4 (B-reads of that buf end at P2). Counted
// vmcnt(4) once per group retires tile g+1 before its reads; never 0 mid-loop.
// Conflict-free LDS: pre-swizzled global source slot ((l&7)-(l>>3))&7, read
// slot ((ks*4+hi)+(fr&7))&7 — linear gload_lds dest (rule #21 both-sides).
// Split epilogue: zb / xbcb / dtraw, cols >= DPROJ dropped.
// ---------------------------------------------------------------------------
__global__ __launch_bounds__(512, 2) void gemm256_inproj(
    const short* __restrict__ A, const short* __restrict__ Bt,
    bf16* __restrict__ zb, bf16* __restrict__ xbcb, float* __restrict__ dtraw) {
  extern __shared__ short smem[];
  short* AslS = smem;                  // [2][256*64]
  short* BslS = smem + 2 * 256 * 64;   // [2][256*64]
  const int t = threadIdx.x;
  const int l = t & 63;
  const int wid = t >> 6;              // 0..7
  const int wr = wid >> 2, wc = wid & 3;

  int bid = blockIdx.y * GX2 + blockIdx.x;
  bid = (bid & 7) * (NWG2 / 8) + (bid >> 3);   // bijective XCD swizzle
  const int m0 = (bid / GX2) * 256;
  const int n0 = (bid % GX2) * 256;

  // staging lane geometry: chunk row = l>>3, phys slot = l&7, pre-swz source
  const int srow  = l >> 3;
  const int sslot = ((l & 7) - srow) & 7;
  const short* gAl = A  + (size_t)(m0 + srow) * DM + sslot * 8;
  const short* gBl = Bt + (size_t)(n0 + srow) * DM + sslot * 8;

  const int fr = l & 15, hi = l >> 4;

  f32x4 acc[8][4] = {};
  short8 afr[4][2], bfr[4][2];

  auto stageA = [&](int kt, int h) {
    const int buf = kt & 1;
#pragma unroll
    for (int q = 0; q < 2; ++q) {
      int rbase = h * 128 + (wid * 2 + q) * 8;
      gload16(gAl + (size_t)rbase * DM + kt * 64,
              AslS + buf * (256 * 64) + rbase * 64);
    }
  };
  auto stageB = [&](int kt, int h) {
    const int buf = kt & 1;
#pragma unroll
    for (int q = 0; q < 2; ++q) {
      int rbase = h * 128 + (wid * 2 + q) * 8;
      gload16(gBl + (size_t)rbase * DM + kt * 64,
              BslS + buf * (256 * 64) + rbase * 64);
    }
  };
  auto rdA = [&](int kt, int i, int ks) -> short8 {
    int row = wr * 128 + i * 16 + fr;
    int ps  = ((ks * 4 + hi) + (fr & 7)) & 7;
    return *(const short8*)&AslS[(kt & 1) * (256 * 64) + row * 64 + ps * 8];
  };
  auto rdB = [&](int kt, int j, int ks) -> short8 {
    int row = wc * 64 + j * 16 + fr;
    int ps  = ((ks * 4 + hi) + (fr & 7)) & 7;
    return *(const short8*)&BslS[(kt & 1) * (256 * 64) + row * 64 + ps * 8];
  };

  // prologue: B(0), A(0), B(1); wait tile 0 (4 in flight = B(1)); barrier
  stageB(0, 0); stageB(0, 1);
  stageA(0, 0); stageA(0, 1);
  stageB(1, 0); stageB(1, 1);
  waitvm<4>();
  barrier_raw();

  for (int g = 0; g < NT2; ++g) {
    // ---- P1: read A i0-3 + B j0-1 (tile g); stage A0(g+1)
#pragma unroll
    for (int i = 0; i < 4; ++i) { afr[i][0] = rdA(g, i, 0); afr[i][1] = rdA(g, i, 1); }
#pragma unroll
    for (int j = 0; j < 2; ++j) { bfr[j][0] = rdB(g, j, 0); bfr[j][1] = rdB(g, j, 1); }
    if (g + 1 < NT2) stageA(g + 1, 0);
    barrier_raw();
    __builtin_amdgcn_s_setprio(1);
#pragma unroll
    for (int i = 0; i < 4; ++i)
#pragma unroll
      for (int j = 0; j < 2; ++j) {
        acc[i][j] = __builtin_amdgcn_mfma_f32_16x16x32_bf16(afr[i][0], bfr[j][0], acc[i][j], 0, 0, 0);
        acc[i][j] = __builtin_amdgcn_mfma_f32_16x16x32_bf16(afr[i][1], bfr[j][1], acc[i][j], 0, 0, 0);
      }
    __builtin_amdgcn_s_setprio(0);
    barrier_raw();
    // ---- P2: read B j2-3; stage A1(g+1)
#pragma unroll
    for (int j = 2; j < 4; ++j) { bfr[j][0] = rdB(g, j, 0); bfr[j][1] = rdB(g, j, 1); }
    if (g + 1 < NT2) stageA(g + 1, 1);
    barrier_raw();
    __builtin_amdgcn_s_setprio(1);
#pragma unroll
    for (int i = 0; i < 4; ++i)
#pragma unroll
      for (int j = 2; j < 4; ++j) {
        acc[i][j] = __builtin_amdgcn_mfma_f32_16x16x32_bf16(afr[i][0], bfr[j][0], acc[i][j], 0, 0, 0);
        acc[i][j] = __builtin_amdgcn_mfma_f32_16x16x32_bf16(afr[i][1], bfr[j][1], acc[i][j], 0, 0, 0);
      }
    __builtin_amdgcn_s_setprio(0);
    barrier_raw();
    // ---- P3: read A i4-7 (reuse afr); stage B0(g+2)
#pragma unroll
    for (int i = 0; i < 4; ++i) { afr[i][0] = rdA(g, 4 + i, 0); afr[i][1] = rdA(g, 4 + i, 1); }
    if (g + 2 < NT2) stageB(g + 2, 0);
    barrier_raw();
    __builtin_amdgcn_s_setprio(1);
#pragma unroll
    for (int i = 0; i < 4; ++i)
#pragma unroll
      for (int j = 0; j < 2; ++j) {
        acc[4 + i][j] = __builtin_amdgcn_mfma_f32_16x16x32_bf16(afr[i][0], bfr[j][0], acc[4 + i][j], 0, 0, 0);
        acc[4 + i][j] = __builtin_amdgcn_mfma_f32_16x16x32_bf16(afr[i][1], bfr[j][1], acc[4 + i][j], 0, 0, 0);
      }
    __builtin_amdgcn_s_setprio(0);
    barrier_raw();
    // ---- P4: stage B1(g+2); counted wait (retire tile g+1); MFMA
    if (g + 2 < NT2) stageB(g + 2, 1);
    if (g + 2 < NT2)      waitvm<4>();
    else if (g + 1 < NT2) waitvm<0>();
    barrier_raw();
    __builtin_amdgcn_s_setprio(1);
#pragma unroll
    for (int i = 0; i < 4; ++i)
#pragma unroll
      for (int j = 2; j < 4; ++j) {
        acc[4 + i][j] = __builtin_amdgcn_mfma_f32_16x16x32_bf16(afr[i][0], bfr[j][0], acc[4 + i][j], 0, 0, 0);
        acc[4 + i][j] = __builtin_amdgcn_mfma_f32_16x16x32_bf16(afr[i][1], bfr[j][1], acc[4 + i][j], 0, 0, 0);
      }
    __builtin_amdgcn_s_setprio(0);
    barrier_raw();
  }

  // epilogue: D col = lane&15, row = (lane>>4)*4 + q; split store
#pragma unroll
  for (int i = 0; i < 8; ++i) {
#pragma unroll
    for (int j = 0; j < 4; ++j) {
      int gcol  = n0 + wc * 64 + j * 16 + fr;
      int grow0 = m0 + wr * 128 + i * 16 + hi * 4;
#pragma unroll
      for (int q = 0; q < 4; ++q) {
        float v = acc[i][j][q];
        int grow = grow0 + q;
        if (gcol < DIN) {
          zb[(size_t)grow * DIN + gcol] = f2b(v);
        } else if (gcol < DIN + CONVD) {
          xbcb[(size_t)grow * CONVD + (gcol - DIN)] = f2b(v);
        } else if (gcol < DPROJ) {
          dtraw[(size_t)grow * HH + (gcol - DIN - CONVD)] = v;
        }
      }
    }
  }
}

// ---------------------------------------------------------------------------
// bf16 MFMA GEMM 64x128 (out_proj), 3-buffer single-barrier pipeline (R8).
// ---------------------------------------------------------------------------
__global__ __launch_bounds__(256) void gemm_out(
    const short* __restrict__ A, const short* __restrict__ Bt,
    float* __restrict__ Cout) {
  constexpr int K = DIN;
  constexpr int GX = DM / 128, GY = ROWS / 64;
  constexpr int NWG = GX * GY, CPX = NWG / 8;
  __shared__ short Asl[3][64 * 32];
  __shared__ short Bsl[3][128 * 32];
  const int t = threadIdx.x;
  const int l = t & 63;
  const int w = t >> 6;
  const int wr = w >> 1, wc = w & 1;

  int bid = blockIdx.y * GX + blockIdx.x;
  bid = (bid & 7) * CPX + (bid >> 3);
  const int m0 = (bid / GX) * 64;
  const int n0 = (bid % GX) * 128;

  const int srow = l >> 2;
  const int sk   = (((l & 3) - ((l >> 3) & 3)) & 3) * 8;
  const short* gA0 = &A [(size_t)(m0 + w * 16 + srow) * K + sk];
  const short* gB0 = &Bt[(size_t)(n0 + w * 16 + srow) * K + sk];
  const short* gB1 = &Bt[(size_t)(n0 + (4 + w) * 16 + srow) * K + sk];
  const int ldsW0 = (w * 16) * 32, ldsW1 = ((4 + w) * 16) * 32;

  auto STAGE = [&](int buf) {
    gload16(gA0, &Asl[buf][ldsW0]);
    gload16(gB0, &Bsl[buf][ldsW0]);
    gload16(gB1, &Bsl[buf][ldsW1]);
    gA0 += 32; gB0 += 32; gB1 += 32;
  };

  const int fr = l & 15;
  const int s2 = (((l >> 4) + ((fr >> 1) & 3)) & 3) * 8;
  const int aoff = (wr * 32 + fr) * 32 + s2;
  const int boff = (wc * 64 + fr) * 32 + s2;

  f32x4 acc[2][4] = {};
  const int nt = K >> 5;

  STAGE(0);
  for (int ti = 0; ti < nt; ++ti) {
    const int cur = ti % 3;
    if (ti + 1 < nt) { STAGE((ti + 1) % 3); waitvm<3>(); }
    else             { waitvm<0>(); }
    barrier_raw();
    short8 af[2], bg[4];
#pragma unroll
    for (int i = 0; i < 2; ++i) af[i] = *(const short8*)&Asl[cur][aoff + i * 512];
#pragma unroll
    for (int j = 0; j < 4; ++j) bg[j] = *(const short8*)&Bsl[cur][boff + j * 512];
#pragma unroll
    for (int i = 0; i < 2; ++i)
#pragma unroll
      for (int j = 0; j < 4; ++j)
        acc[i][j] = __builtin_amdgcn_mfma_f32_16x16x32_bf16(af[i], bg[j],
                                                            acc[i][j], 0, 0, 0);
  }
#pragma unroll
  for (int i = 0; i < 2; ++i)
#pragma unroll
    for (int j = 0; j < 4; ++j) {
      int gcol = n0 + wc * 64 + j * 16 + (l & 15);
      int grow0 = m0 + wr * 32 + i * 16 + (l >> 4) * 4;
#pragma unroll
      for (int q = 0; q < 4; ++q)
        Cout[(size_t)(grow0 + q) * DM + gcol] = acc[i][j][q];
    }
}

// ---------------------------------------------------------------------------
// Depthwise causal conv1d (k=4) + bias + silu + splits; dt softplus; dtA.
// ---------------------------------------------------------------------------
__global__ __launch_bounds__(256) void conv_act(
    const bf16* __restrict__ xbc, const float* __restrict__ dtraw,
    const float* __restrict__ convw, const float* __restrict__ convb,
    const float* __restrict__ dtb, const float* __restrict__ alog,
    bf16* __restrict__ xs, bf16* __restrict__ Bb, bf16* __restrict__ Cb,
    float* __restrict__ dtv, float* __restrict__ dtA) {
  const int row = blockIdx.x;
  const int l   = row & (LL - 1);
  const int t   = threadIdx.x;
  if (t < HH) {
    float raw = dtraw[(size_t)row * HH + t] + dtb[t];
    float dt  = (raw > 20.f) ? raw : log1pf(expf(raw));
    dtv[(size_t)row * HH + t] = dt;
    dtA[(size_t)row * HH + t] = -expf(alog[t]) * dt;
  }
  for (int ch = t * 8; ch < CONVD; ch += 2048) {
    float acc[8];
#pragma unroll
    for (int j = 0; j < 8; ++j) acc[j] = convb[ch + j];
#pragma unroll
    for (int k = 0; k < 4; ++k) {
      if (l - 3 + k >= 0) {
        uint4 v = *(const uint4*)&xbc[(size_t)(row - 3 + k) * CONVD + ch];
        const bf16* pv = (const bf16*)&v;
        const float* wp = &convw[k * CONVD + ch];
#pragma unroll
        for (int j = 0; j < 8; ++j) acc[j] += b2f(pv[j]) * wp[j];
      }
    }
    short8 sv;
#pragma unroll
    for (int j = 0; j < 8; ++j) {
      float s = acc[j] / (1.f + expf(-acc[j])); // silu
      sv[j] = f2bs(s);
    }
    if (ch < DIN) {
      *(short8*)&xs[(size_t)row * DIN + ch] = sv;
    } else if (ch < DIN + NSD) {
      *(short8*)&Bb[(size_t)row * NSD + (ch - DIN)] = sv;
    } else {
      *(short8*)&Cb[(size_t)row * NSD + (ch - DIN - NSD)] = sv;
    }
  }
}

// ---------------------------------------------------------------------------
// G[b,c,l,s] = dot(C[l,:], B[s,:]) — MFMA. One block per (b,c).
// ---------------------------------------------------------------------------
__global__ __launch_bounds__(256) void gmat(const bf16* __restrict__ Bb,
                                            const bf16* __restrict__ Cb,
                                            float* __restrict__ G) {
  const int c = blockIdx.x, b = blockIdx.y;
  const int row0 = (b * NC + c) * CHK;
  __shared__ short Csh[64][136];
  __shared__ short Bsh[64][136];
  const int t = threadIdx.x;
  const int lane = t & 63, w = t >> 6;
#pragma unroll
  for (int i = 0; i < 4; ++i) {
    int f = t + i * 256;
    int rr = f >> 4, n0 = (f & 15) * 8;
    *(uint4*)&Csh[rr][n0] = *(const uint4*)&Cb[(size_t)(row0 + rr) * NSD + n0];
    *(uint4*)&Bsh[rr][n0] = *(const uint4*)&Bb[(size_t)(row0 + rr) * NSD + n0];
  }
  __syncthreads();
  f32x4 acc[4] = {};
  const int r = lane & 15, hi = lane >> 4;
#pragma unroll
  for (int kk = 0; kk < 4; ++kk) {
    short8 af = *(const short8*)&Csh[16 * w + r][kk * 32 + hi * 8];
#pragma unroll
    for (int j = 0; j < 4; ++j) {
      short8 bg = *(const short8*)&Bsh[16 * j + r][kk * 32 + hi * 8];
      acc[j] = __builtin_amdgcn_mfma_f32_16x16x32_bf16(af, bg, acc[j], 0, 0, 0);
    }
  }
#pragma unroll
  for (int j = 0; j < 4; ++j)
#pragma unroll
    for (int q = 0; q < 4; ++q) {
      int ll = 16 * w + hi * 4 + q, ss = 16 * j + r;
      G[((size_t)(b * NC + c) * CHK + ll) * CHK + ss] = acc[j][q];
    }
}

// ---------------------------------------------------------------------------
// Per (b,c,h): cumsum(dtA) via Kogge-Stone; Y_diag (MFMA); states (MFMA).
// ---------------------------------------------------------------------------
__global__ __launch_bounds__(256) void ssd_chunk(
    const float* __restrict__ G, const bf16* __restrict__ xsp,
    const bf16* __restrict__ Bb, const float* __restrict__ dtv,
    const float* __restrict__ dtA,
    bf16* __restrict__ y, bf16* __restrict__ states, float* __restrict__ cumA) {
  const int h = blockIdx.x, c = blockIdx.y, b = blockIdx.z;
  const int row0 = (b * NC + c) * CHK;
  __shared__ short GMb[64][72];
  __shared__ short xdsT[64][72];
  __shared__ short BdT[128][72];
  __shared__ float cA[CHK], dec[CHK], sdt[CHK];
  const int t = threadIdx.x;
  const int lane = t & 63, w = t >> 6;
  if (t < CHK) {
    sdt[t] = dtv[(size_t)(row0 + t) * HH + h];
    float v = dtA[(size_t)(row0 + t) * HH + h];
#pragma unroll
    for (int o = 1; o < 64; o <<= 1) {
      float u = __shfl_up(v, o, 64);
      if (t >= o) v += u;
    }
    cA[t] = v;
  }
  __syncthreads();
  if (t < CHK) {
    dec[t] = expf(cA[CHK - 1] - cA[t]);
    cumA[((size_t)(b * HH + h) * NC + c) * CHK + t] = cA[t];
  }
#pragma unroll
  for (int i = 0; i < 2; ++i) {
    int f = t + i * 256;
    int ll = f >> 3, p0 = (f & 7) * 8;
    uint4 v = *(const uint4*)&xsp[(size_t)(row0 + ll) * DIN + h * PP + p0];
    const bf16* pv = (const bf16*)&v;
    float dtl = sdt[ll];
#pragma unroll
    for (int j = 0; j < 8; ++j) xdsT[p0 + j][ll] = f2bs(b2f(pv[j]) * dtl);
  }
#pragma unroll
  for (int i = 0; i < 4; ++i) {
    int f = t + i * 256;
    int ll = f >> 4, s0 = (f & 15) * 4;
    float4 g = *(const float4*)&G[((size_t)(b * NC + c) * CHK + ll) * CHK + s0];
    float ca = cA[ll];
    GMb[ll][s0 + 0] = f2bs((s0 + 0 <= ll) ? g.x * expf(ca - cA[s0 + 0]) : 0.f);
    GMb[ll][s0 + 1] = f2bs((s0 + 1 <= ll) ? g.y * expf(ca - cA[s0 + 1]) : 0.f);
    GMb[ll][s0 + 2] = f2bs((s0 + 2 <= ll) ? g.z * expf(ca - cA[s0 + 2]) : 0.f);
    GMb[ll][s0 + 3] = f2bs((s0 + 3 <= ll) ? g.w * expf(ca - cA[s0 + 3]) : 0.f);
  }
  __syncthreads();
#pragma unroll
  for (int i = 0; i < 4; ++i) {
    int f = t + i * 256;
    int ll = f >> 4, n0 = (f & 15) * 8;
    uint4 v = *(const uint4*)&Bb[(size_t)(row0 + ll) * NSD + n0];
    const bf16* pv = (const bf16*)&v;
    float dl = dec[ll];
#pragma unroll
    for (int j = 0; j < 8; ++j) BdT[n0 + j][ll] = f2bs(b2f(pv[j]) * dl);
  }
  __syncthreads();
  const int r = lane & 15, hi = lane >> 4;
  {
    f32x4 acc[4] = {};
#pragma unroll
    for (int kk = 0; kk < 2; ++kk) {
      short8 af = *(const short8*)&GMb[16 * w + r][kk * 32 + hi * 8];
#pragma unroll
      for (int j = 0; j < 4; ++j) {
        short8 bg = *(const short8*)&xdsT[16 * j + r][kk * 32 + hi * 8];
        acc[j] = __builtin_amdgcn_mfma_f32_16x16x32_bf16(af, bg, acc[j], 0, 0, 0);
      }
    }
#pragma unroll
    for (int j = 0; j < 4; ++j)
#pragma unroll
      for (int q = 0; q < 4; ++q) {
        int ll = 16 * w + hi * 4 + q, pp = 16 * j + r;
        y[(size_t)(row0 + ll) * DIN + h * PP + pp] = f2b(acc[j][q]);
      }
  }
  {
    f32x4 acc[8] = {};
#pragma unroll
    for (int kk = 0; kk < 2; ++kk) {
      short8 af = *(const short8*)&xdsT[16 * w + r][kk * 32 + hi * 8];
#pragma unroll
      for (int j = 0; j < 8; ++j) {
        short8 bg = *(const short8*)&BdT[16 * j + r][kk * 32 + hi * 8];
        acc[j] = __builtin_amdgcn_mfma_f32_16x16x32_bf16(af, bg, acc[j], 0, 0, 0);
      }
    }
    size_t sb = ((size_t)(b * NC + c) * HH + h) * (PP * NSD);
#pragma unroll
    for (int j = 0; j < 8; ++j)
#pragma unroll
      for (int q = 0; q < 4; ++q) {
        int pp = 16 * w + hi * 4 + q, nn = 16 * j + r;
        states[sb + (size_t)pp * NSD + nn] = f2b(acc[j][q]);
      }
  }
}

// ---------------------------------------------------------------------------
// Inter-chunk sequential scan, in place (bf16 storage, fp32 carry).
// ---------------------------------------------------------------------------
__global__ __launch_bounds__(256) void scan(bf16* __restrict__ states,
                                            const float* __restrict__ cumA) {
  const int q = blockIdx.x, h = blockIdx.y, b = blockIdx.z;
  const int t = threadIdx.x;
  const int off = q * 2048 + t * 8;
  const size_t cstride = (size_t)HH * PP * NSD;
  size_t base = ((size_t)(b * NC) * HH + h) * (PP * NSD) + off;
  const float* cp = &cumA[(size_t)(b * HH + h) * NC * CHK + CHK - 1];
  float S[8] = {};
  uint4 nv = *(const uint4*)&states[base];
  for (int c = 0; c < NC; ++c) {
    uint4 cv = nv;
    if (c + 1 < NC) nv = *(const uint4*)&states[base + cstride];
    float tot = expf(cp[(size_t)c * CHK]);
    const bf16* pin = (const bf16*)&cv;
    short8 sv;
#pragma unroll
    for (int i = 0; i < 8; ++i) {
      float cs = b2f(pin[i]);
      sv[i] = f2bs(S[i]);
      S[i] = S[i] * tot + cs;
    }
    *(short8*)&states[base] = sv;
    base += cstride;
  }
}

// ---------------------------------------------------------------------------
// Y_off[l][p] = dot(C[l,:], S[p,:]) — MFMA; y += Y_off*exp(cA) + xs*D.
// ---------------------------------------------------------------------------
__global__ __launch_bounds__(256) void yoff(
    const bf16* __restrict__ Cb, const bf16* __restrict__ states,
    const float* __restrict__ cumA, const bf16* __restrict__ xs,
    const float* __restrict__ Dp, bf16* __restrict__ y) {
  const int h = blockIdx.x, c = blockIdx.y, b = blockIdx.z;
  const int row0 = (b * NC + c) * CHK;
  __shared__ short Csh[64][136];
  __shared__ short Ssh[64][136];
  __shared__ float dcy[CHK];
  const int t = threadIdx.x;
  const int lane = t & 63, w = t >> 6;
  if (t < CHK) dcy[t] = expf(cumA[((size_t)(b * HH + h) * NC + c) * CHK + t]);
  const size_t sbase = ((size_t)(b * NC + c) * HH + h) * (PP * NSD);
#pragma unroll
  for (int i = 0; i < 4; ++i) {
    int f = t + i * 256;
    int rr = f >> 4, n0 = (f & 15) * 8;
    *(uint4*)&Csh[rr][n0] = *(const uint4*)&Cb[(size_t)(row0 + rr) * NSD + n0];
    *(uint4*)&Ssh[rr][n0] = *(const uint4*)&states[sbase + (size_t)rr * NSD + n0];
  }
  __syncthreads();
  f32x4 acc[4] = {};
  const int r = lane & 15, hi = lane >> 4;
#pragma unroll
  for (int kk = 0; kk < 4; ++kk) {
    short8 af = *(const short8*)&Csh[16 * w + r][kk * 32 + hi * 8];
#pragma unroll
    for (int j = 0; j < 4; ++j) {
      short8 bg = *(const short8*)&Ssh[16 * j + r][kk * 32 + hi * 8];
      acc[j] = __builtin_amdgcn_mfma_f32_16x16x32_bf16(af, bg, acc[j], 0, 0, 0);
    }
  }
  const float Dh = Dp[h];
#pragma unroll
  for (int j = 0; j < 4; ++j)
#pragma unroll
    for (int q = 0; q < 4; ++q) {
      int ll = 16 * w + hi * 4 + q, pp = 16 * j + r;
      size_t idx = (size_t)(row0 + ll) * DIN + h * PP + pp;
      y[idx] = f2b(b2f(y[idx]) + acc[j][q] * dcy[ll] + b2f(xs[idx]) * Dh);
    }
}

// ---------------------------------------------------------------------------
// yz = y * silu(z); RMS-normalize over d_inner; scale; bf16 out. Vectorized.
// ---------------------------------------------------------------------------
__global__ __launch_bounds__(256) void gatenorm(const bf16* __restrict__ y,
                                                const bf16* __restrict__ zb,
                                                const float* __restrict__ nsc,
                                                bf16* __restrict__ outn) {
  const int row = blockIdx.x, t = threadIdx.x;
  const int ch = t * 8;
  uint4 yv4 = *(const uint4*)&y [(size_t)row * DIN + ch];
  uint4 zv4 = *(const uint4*)&zb[(size_t)row * DIN + ch];
  const bf16* yp = (const bf16*)&yv4;
  const bf16* zp = (const bf16*)&zv4;
  float v[8];
  float ss = 0.f;
#pragma unroll
  for (int i = 0; i < 8; ++i) {
    float z  = b2f(zp[i]);
    float g  = b2f(yp[i]) * z / (1.f + expf(-z));
    v[i] = g;
    ss += g * g;
  }
#pragma unroll
  for (int off = 32; off > 0; off >>= 1) ss += __shfl_down(ss, off, 64);
  __shared__ float red[4];
  if ((t & 63) == 0) red[t >> 6] = ss;
  __syncthreads();
  float tot = red[0] + red[1] + red[2] + red[3];
  float r = rsqrtf(tot * (1.f / DIN) + 1e-6f);
  short8 o;
#pragma unroll
  for (int i = 0; i < 8; ++i) o[i] = f2bs(v[i] * r * nsc[ch + i]);
  *(short8*)&outn[(size_t)row * DIN + ch] = o;
}

// ---------------------------------------------------------------------------
extern "C" void kernel_launch(void* const* d_in, const int* in_sizes, int n_in,
                              void* d_out, int out_size, void* d_ws, size_t ws_size,
                              hipStream_t stream) {
  const float* x     = (const float*)d_in[0];
  const float* inw   = (const float*)d_in[1];
  const float* convw = (const float*)d_in[2];
  const float* convb = (const float*)d_in[3];
  const float* dtb   = (const float*)d_in[4];
  const float* alog  = (const float*)d_in[5];
  const float* Dp    = (const float*)d_in[6];
  const float* nsc   = (const float*)d_in[7];
  const float* outw  = (const float*)d_in[8];
  float* out = (float*)d_out;

  // workspace layout — ~210 MB total (bf16 intermediates, aliased reuse)
  char* p = (char*)d_ws;
  bf16*  zb     = (bf16*)p;  p += (size_t)ROWS * DIN * 2;          //  33.6 MB
  bf16*  xbcb   = (bf16*)p;  p += (size_t)ROWS * CONVD * 2;        //  37.7 MB
  bf16*  y      = xbcb;      // reuse: conv consumes xbcb before y is written
  float* dtraw  = (float*)p; p += (size_t)ROWS * HH * 4;           //   1.0 MB
  bf16*  xs     = (bf16*)p;  p += (size_t)ROWS * DIN * 2;          //  33.6 MB
  bf16*  states = (bf16*)p;  p += (size_t)BB * NC * HH * PP * NSD * 2; // 67.1 MB
  bf16*  normb  = states;    // reuse: yoff consumes states before norm written
  bf16*  Bb     = (bf16*)p;  p += (size_t)ROWS * NSD * 2;          //   2.1 MB
  bf16*  Cb     = (bf16*)p;  p += (size_t)ROWS * NSD * 2;          //   2.1 MB
  float* dtv    = (float*)p; p += (size_t)ROWS * HH * 4;           //   1.0 MB
  float* dtA    = (float*)p; p += (size_t)ROWS * HH * 4;           //   1.0 MB
  float* cumA   = (float*)p; p += (size_t)BB * HH * NC * CHK * 4;  //   1.0 MB
  float* G      = (float*)p; p += (size_t)BB * NC * CHK * CHK * 4; //   2.1 MB
  bf16*  xb     = (bf16*)p;  p += (size_t)ROWS * DM * 2;           //  16.8 MB
  bf16*  BtIn   = (bf16*)p;  p += (size_t)NPAD2 * DM * 2;          //   9.4 MB
  bf16*  BtOut  = xb;        // reuse: xb dead after in_proj GEMM

  // allow 128 KiB dynamic LDS for the 8-phase GEMM (idempotent host call)
  (void)hipFuncSetAttribute((const void*)gemm256_inproj,
                            hipFuncAttributeMaxDynamicSharedMemorySize, 131072);

  // 0a. x -> bf16
  convert_bf16<<<(ROWS * DM / 4 + 255) / 256, 256, 0, stream>>>(x, xb, ROWS * DM / 4);
  // 0b. in_proj_w [DM][DPROJ] -> BtIn bf16 [NPAD2][DM]
  transpose_w<<<dim3(NPAD2 / 32, DM / 32), 256, 0, stream>>>(inw, BtIn, DM, DPROJ);
  // 1. in_proj GEMM (256-sq 8-phase MFMA, split outputs)
  gemm256_inproj<<<dim3(GX2, GY2), 512, 131072, stream>>>(
      (const short*)xb, (const short*)BtIn, zb, xbcb, dtraw);
  // 0c. out_proj_w [DIN][DM] -> BtOut bf16 [DM][DIN]  (into dead xb region)
  transpose_w<<<dim3(DM / 32, DIN / 32), 256, 0, stream>>>(outw, BtOut, DIN, DM);
  // 2. conv + activations + splits (bf16 B/C)
  conv_act<<<ROWS, 256, 0, stream>>>(xbcb, dtraw, convw, convb, dtb, alog,
                                     xs, Bb, Cb, dtv, dtA);
  // 3. G = C B^T per chunk (MFMA)
  gmat<<<dim3(NC, BB), 256, 0, stream>>>(Bb, Cb, G);
  // 4. Y_diag + chunk states per (b,c,h) (MFMA; y overwrites xbcb region)
  ssd_chunk<<<dim3(HH, NC, BB), 256, 0, stream>>>(G, xs, Bb, dtv, dtA,
                                                  y, states, cumA);
  // 5. inter-chunk scan (in place, vectorized + prefetch)
  scan<<<dim3(4, HH, BB), 256, 0, stream>>>(states, cumA);
  // 6. Y_off + D-term (MFMA)
  yoff<<<dim3(HH, NC, BB), 256, 0, stream>>>(Cb, states, cumA, xs, Dp, y);
  // 7. gate + RMSNorm (normed overwrites states region)
  gatenorm<<<ROWS, 256, 0, stream>>>(y, zb, nsc, normb);
  // 8. out_proj GEMM (64x128 single-barrier pipeline, fp32 out)
  gemm_out<<<dim3(DM / 128, ROWS / 64), 256, 0, stream>>>(
      (const short*)normb, (const short*)BtOut, out);

  (void)in_sizes; (void)n_in; (void)out_size; (void)ws_size;
}

// Round 11
// 336.986 us; speedup vs baseline: 1.0445x; 1.0445x over previous
//
#include <hip/hip_runtime.h>
#include <hip/hip_bf16.h>
#include <math.h>

typedef __hip_bfloat16 bf16;
typedef __attribute__((ext_vector_type(8))) short short8;
typedef __attribute__((ext_vector_type(4))) float f32x4;

constexpr int BB    = 2;      // batch
constexpr int LL    = 4096;   // seq len
constexpr int DM    = 1024;   // d_model
constexpr int DIN   = 2048;   // d_inner
constexpr int HH    = 32;     // n_heads
constexpr int PP    = 64;     // head_dim
constexpr int NSD   = 128;    // d_state
constexpr int CONVD = 2304;   // d_inner + 2*d_state
constexpr int DPROJ = 4384;   // 2*d_inner + 2*d_state + n_heads
constexpr int NPAD  = 4480;   // DPROJ padded to 35*128
constexpr int CHK   = 64;     // chunk size
constexpr int NC    = 64;     // chunks per batch (L/CHK)
constexpr int ROWS  = BB * LL; // 8192

__device__ __forceinline__ float b2f(bf16 v) { return __bfloat162float(v); }
__device__ __forceinline__ bf16  f2b(float f) { return __float2bfloat16(f); }
__device__ __forceinline__ short f2bs(float f) {
  bf16 b = f2b(f);
  return *reinterpret_cast<short*>(&b);
}
// async global->LDS, 16B per lane; LDS dest = base + lane*16 (wave-uniform base)
__device__ __forceinline__ void gload16(const short* g, short* l) {
  __builtin_amdgcn_global_load_lds(
      (const __attribute__((address_space(1))) void*)g,
      (__attribute__((address_space(3))) void*)l, 16, 0, 0);
}
template <int N> __device__ __forceinline__ void waitvm() {
  if constexpr (N == 0)      asm volatile("s_waitcnt vmcnt(0)" ::: "memory");
  else if constexpr (N == 3) asm volatile("s_waitcnt vmcnt(3)" ::: "memory");
  else                       asm volatile("s_waitcnt vmcnt(4)" ::: "memory");
}
__device__ __forceinline__ void barrier_raw() {
  asm volatile("s_barrier" ::: "memory");
}

// ---------------------------------------------------------------------------
// fp32 -> bf16 elementwise. 4 elems/thread.
// ---------------------------------------------------------------------------
__global__ __launch_bounds__(256) void convert_bf16(const float* __restrict__ in,
                                                    bf16* __restrict__ outp, int n4) {
  int i = blockIdx.x * 256 + threadIdx.x;
  if (i >= n4) return;
  float4 v = *(const float4*)&in[(size_t)i * 4];
  bf16* p = &outp[(size_t)i * 4];
  p[0] = f2b(v.x); p[1] = f2b(v.y); p[2] = f2b(v.z); p[3] = f2b(v.w);
}

// ---------------------------------------------------------------------------
// Transpose + convert: W fp32 [K][N] row-major -> Bt bf16 [Npad][K] row-major.
// ---------------------------------------------------------------------------
__global__ __launch_bounds__(256) void transpose_w(const float* __restrict__ W,
                                                   bf16* __restrict__ Bt,
                                                   int K, int N) {
  __shared__ float Tl[32][33];
  const int n0 = blockIdx.x * 32, k0 = blockIdx.y * 32;
  const int t = threadIdx.x;
  {
    const int kk = t >> 3, nn4 = (t & 7) * 4;
#pragma unroll
    for (int j = 0; j < 4; ++j) {
      int n = n0 + nn4 + j;
      Tl[kk][nn4 + j] = (n < N) ? W[(size_t)(k0 + kk) * N + n] : 0.f;
    }
  }
  __syncthreads();
  {
    const int nn = t >> 3, kk4 = (t & 7) * 4;
#pragma unroll
    for (int j = 0; j < 4; ++j)
      Bt[(size_t)(n0 + nn) * K + k0 + kk4 + j] = f2b(Tl[kk4 + j][nn]);
  }
}

// ---------------------------------------------------------------------------
// bf16 MFMA GEMM, (MI*32)x128 tile, BK=32, 4 waves (2x2), MI x 4 16x16x32
// tiles/wave. 3-buffer LDS, SINGLE barrier per K-step (R8, proven 109 us):
//   iter ti:  STAGE(ti+1 -> buf[(ti+1)%3]) -> vmcnt(NL) -> s_barrier
//             -> ds_read + MFMA on buf[ti%3]
// Pre-swizzled global source + swizzled read (conflict-free). Bijective XCD
// swizzle. MODE 0 (MI=4): split store zb/xbcb/dtraw. MODE 1 (MI=2): fp32 C.
// ---------------------------------------------------------------------------
template <int MODE, int MI>
__global__ __launch_bounds__(256) void gemm_mfma(
    const short* __restrict__ A, const short* __restrict__ Bt, int K,
    bf16* __restrict__ zb, bf16* __restrict__ xbcb,
    float* __restrict__ dtraw, float* __restrict__ Cout) {
  constexpr int MROWS = MI * 32;        // A-tile rows (128 or 64)
  constexpr int NL = (MI == 4) ? 4 : 3; // gloads per wave per tile
  constexpr int GX = (MODE == 0) ? NPAD / 128 : DM / 128;   // grid x
  constexpr int GY = (MODE == 0) ? ROWS / 128 : ROWS / 64;  // grid y
  constexpr int NWG = GX * GY;          // 2240 / 1024, both % 8 == 0
  constexpr int CPX = NWG / 8;
  __shared__ short Asl[3][MROWS * 32];
  __shared__ short Bsl[3][128 * 32];
  const int t = threadIdx.x;
  const int l = t & 63;
  const int w = t >> 6;
  const int wr = w >> 1, wc = w & 1;

  int bid = blockIdx.y * GX + blockIdx.x;
  bid = (bid & 7) * CPX + (bid >> 3);
  const int m0 = (bid / GX) * MROWS;
  const int n0 = (bid % GX) * 128;

  const int srow = l >> 2;
  const int sk   = (((l & 3) - ((l >> 3) & 3)) & 3) * 8;  // shorts
  const short* gA0 = &A [(size_t)(m0 + w * 16 + srow) * K + sk];
  const short* gA1 = (MI == 4) ? &A[(size_t)(m0 + (4 + w) * 16 + srow) * K + sk]
                               : gA0;
  const short* gB0 = &Bt[(size_t)(n0 + w * 16 + srow) * K + sk];
  const short* gB1 = &Bt[(size_t)(n0 + (4 + w) * 16 + srow) * K + sk];
  const int ldsW0 = (w * 16) * 32, ldsW1 = ((4 + w) * 16) * 32;

  auto STAGE = [&](int buf) {
    gload16(gA0, &Asl[buf][ldsW0]);
    if constexpr (MI == 4) gload16(gA1, &Asl[buf][ldsW1]);
    gload16(gB0, &Bsl[buf][ldsW0]);
    gload16(gB1, &Bsl[buf][ldsW1]);
    gA0 += 32; if constexpr (MI == 4) gA1 += 32;
    gB0 += 32; gB1 += 32;
  };

  const int fr = l & 15;
  const int s2 = (((l >> 4) + ((fr >> 1) & 3)) & 3) * 8;
  const int aoff = (wr * (MI * 16) + fr) * 32 + s2;
  const int boff = (wc * 64 + fr) * 32 + s2;

  f32x4 acc[MI][4] = {};
  const int nt = K >> 5;

  STAGE(0);

  for (int ti = 0; ti < nt; ++ti) {
    const int cur = ti % 3;
    if (ti + 1 < nt) {
      STAGE((ti + 1) % 3);
      waitvm<NL>();
    } else {
      waitvm<0>();
    }
    barrier_raw();
    short8 af[MI], bg[4];
#pragma unroll
    for (int i = 0; i < MI; ++i) af[i] = *(const short8*)&Asl[cur][aoff + i * 512];
#pragma unroll
    for (int j = 0; j < 4; ++j)  bg[j] = *(const short8*)&Bsl[cur][boff + j * 512];
#pragma unroll
    for (int i = 0; i < MI; ++i)
#pragma unroll
      for (int j = 0; j < 4; ++j)
        acc[i][j] = __builtin_amdgcn_mfma_f32_16x16x32_bf16(af[i], bg[j],
                                                            acc[i][j], 0, 0, 0);
  }
#pragma unroll
  for (int i = 0; i < MI; ++i) {
#pragma unroll
    for (int j = 0; j < 4; ++j) {
      int gcol = n0 + wc * 64 + j * 16 + (l & 15);
      int grow0 = m0 + wr * (MI * 16) + i * 16 + (l >> 4) * 4;
#pragma unroll
      for (int q = 0; q < 4; ++q) {
        float v = acc[i][j][q];
        int grow = grow0 + q;
        if constexpr (MODE == 0) {
          if (gcol < DIN) {
            zb[(size_t)grow * DIN + gcol] = f2b(v);
          } else if (gcol < DIN + CONVD) {
            xbcb[(size_t)grow * CONVD + (gcol - DIN)] = f2b(v);
          } else if (gcol < DPROJ) {
            dtraw[(size_t)grow * HH + (gcol - DIN - CONVD)] = v;
          }
        } else {
          Cout[(size_t)grow * DM + gcol] = v;
        }
      }
    }
  }
}

// ---------------------------------------------------------------------------
// Depthwise causal conv1d (k=4) + bias + silu + splits; dt softplus; dtA.
// ---------------------------------------------------------------------------
__global__ __launch_bounds__(256) void conv_act(
    const bf16* __restrict__ xbc, const float* __restrict__ dtraw,
    const float* __restrict__ convw, const float* __restrict__ convb,
    const float* __restrict__ dtb, const float* __restrict__ alog,
    bf16* __restrict__ xs, bf16* __restrict__ Bb, bf16* __restrict__ Cb,
    float* __restrict__ dtv, float* __restrict__ dtA) {
  const int row = blockIdx.x;
  const int l   = row & (LL - 1);
  const int t   = threadIdx.x;
  if (t < HH) {
    float raw = dtraw[(size_t)row * HH + t] + dtb[t];
    float dt  = (raw > 20.f) ? raw : log1pf(expf(raw));
    dtv[(size_t)row * HH + t] = dt;
    dtA[(size_t)row * HH + t] = -expf(alog[t]) * dt;
  }
  for (int ch = t * 8; ch < CONVD; ch += 2048) {
    float acc[8];
#pragma unroll
    for (int j = 0; j < 8; ++j) acc[j] = convb[ch + j];
#pragma unroll
    for (int k = 0; k < 4; ++k) {
      if (l - 3 + k >= 0) {
        uint4 v = *(const uint4*)&xbc[(size_t)(row - 3 + k) * CONVD + ch];
        const bf16* pv = (const bf16*)&v;
        const float* wp = &convw[k * CONVD + ch];
#pragma unroll
        for (int j = 0; j < 8; ++j) acc[j] += b2f(pv[j]) * wp[j];
      }
    }
    short8 sv;
#pragma unroll
    for (int j = 0; j < 8; ++j) {
      float s = acc[j] / (1.f + expf(-acc[j])); // silu
      sv[j] = f2bs(s);
    }
    if (ch < DIN) {
      *(short8*)&xs[(size_t)row * DIN + ch] = sv;
    } else if (ch < DIN + NSD) {
      *(short8*)&Bb[(size_t)row * NSD + (ch - DIN)] = sv;
    } else {
      *(short8*)&Cb[(size_t)row * NSD + (ch - DIN - NSD)] = sv;
    }
  }
}

// ---------------------------------------------------------------------------
// G[b,c,l,s] = dot(C[l,:], B[s,:]) — MFMA. One block per (b,c).
// ---------------------------------------------------------------------------
__global__ __launch_bounds__(256) void gmat(const bf16* __restrict__ Bb,
                                            const bf16* __restrict__ Cb,
                                            float* __restrict__ G) {
  const int c = blockIdx.x, b = blockIdx.y;
  const int row0 = (b * NC + c) * CHK;
  __shared__ short Csh[64][136];
  __shared__ short Bsh[64][136];
  const int t = threadIdx.x;
  const int lane = t & 63, w = t >> 6;
#pragma unroll
  for (int i = 0; i < 4; ++i) {
    int f = t + i * 256;
    int rr = f >> 4, n0 = (f & 15) * 8;
    *(uint4*)&Csh[rr][n0] = *(const uint4*)&Cb[(size_t)(row0 + rr) * NSD + n0];
    *(uint4*)&Bsh[rr][n0] = *(const uint4*)&Bb[(size_t)(row0 + rr) * NSD + n0];
  }
  __syncthreads();
  f32x4 acc[4] = {};
  const int r = lane & 15, hi = lane >> 4;
#pragma unroll
  for (int kk = 0; kk < 4; ++kk) {
    short8 af = *(const short8*)&Csh[16 * w + r][kk * 32 + hi * 8];
#pragma unroll
    for (int j = 0; j < 4; ++j) {
      short8 bg = *(const short8*)&Bsh[16 * j + r][kk * 32 + hi * 8];
      acc[j] = __builtin_amdgcn_mfma_f32_16x16x32_bf16(af, bg, acc[j], 0, 0, 0);
    }
  }
#pragma unroll
  for (int j = 0; j < 4; ++j)
#pragma unroll
    for (int q = 0; q < 4; ++q) {
      int ll = 16 * w + hi * 4 + q, ss = 16 * j + r;
      G[((size_t)(b * NC + c) * CHK + ll) * CHK + ss] = acc[j][q];
    }
}

// ---------------------------------------------------------------------------
// Per (b,c,h): cumsum(dtA) via Kogge-Stone; Y_diag (MFMA) + D-term fused;
// states (MFMA). y = Y_diag + xs*D (exact xs re-read, L2-hot).
// ---------------------------------------------------------------------------
__global__ __launch_bounds__(256) void ssd_chunk(
    const float* __restrict__ G, const bf16* __restrict__ xsp,
    const bf16* __restrict__ Bb, const float* __restrict__ dtv,
    const float* __restrict__ dtA, const float* __restrict__ Dp,
    bf16* __restrict__ y, bf16* __restrict__ states, float* __restrict__ cumA) {
  const int h = blockIdx.x, c = blockIdx.y, b = blockIdx.z;
  const int row0 = (b * NC + c) * CHK;
  __shared__ short GMb[64][72];
  __shared__ short xdsT[64][72];
  __shared__ short BdT[128][72];
  __shared__ float cA[CHK], dec[CHK], sdt[CHK];
  const int t = threadIdx.x;
  const int lane = t & 63, w = t >> 6;
  if (t < CHK) {
    sdt[t] = dtv[(size_t)(row0 + t) * HH + h];
    float v = dtA[(size_t)(row0 + t) * HH + h];
#pragma unroll
    for (int o = 1; o < 64; o <<= 1) {
      float u = __shfl_up(v, o, 64);
      if (t >= o) v += u;
    }
    cA[t] = v;
  }
  __syncthreads();
  if (t < CHK) {
    dec[t] = expf(cA[CHK - 1] - cA[t]);
    cumA[((size_t)(b * HH + h) * NC + c) * CHK + t] = cA[t];
  }
#pragma unroll
  for (int i = 0; i < 2; ++i) {
    int f = t + i * 256;
    int ll = f >> 3, p0 = (f & 7) * 8;
    uint4 v = *(const uint4*)&xsp[(size_t)(row0 + ll) * DIN + h * PP + p0];
    const bf16* pv = (const bf16*)&v;
    float dtl = sdt[ll];
#pragma unroll
    for (int j = 0; j < 8; ++j) xdsT[p0 + j][ll] = f2bs(b2f(pv[j]) * dtl);
  }
#pragma unroll
  for (int i = 0; i < 4; ++i) {
    int f = t + i * 256;
    int ll = f >> 4, s0 = (f & 15) * 4;
    float4 g = *(const float4*)&G[((size_t)(b * NC + c) * CHK + ll) * CHK + s0];
    float ca = cA[ll];
    GMb[ll][s0 + 0] = f2bs((s0 + 0 <= ll) ? g.x * expf(ca - cA[s0 + 0]) : 0.f);
    GMb[ll][s0 + 1] = f2bs((s0 + 1 <= ll) ? g.y * expf(ca - cA[s0 + 1]) : 0.f);
    GMb[ll][s0 + 2] = f2bs((s0 + 2 <= ll) ? g.z * expf(ca - cA[s0 + 2]) : 0.f);
    GMb[ll][s0 + 3] = f2bs((s0 + 3 <= ll) ? g.w * expf(ca - cA[s0 + 3]) : 0.f);
  }
  __syncthreads();
#pragma unroll
  for (int i = 0; i < 4; ++i) {
    int f = t + i * 256;
    int ll = f >> 4, n0 = (f & 15) * 8;
    uint4 v = *(const uint4*)&Bb[(size_t)(row0 + ll) * NSD + n0];
    const bf16* pv = (const bf16*)&v;
    float dl = dec[ll];
#pragma unroll
    for (int j = 0; j < 8; ++j) BdT[n0 + j][ll] = f2bs(b2f(pv[j]) * dl);
  }
  __syncthreads();
  const int r = lane & 15, hi = lane >> 4;
  const float Dh = Dp[h];
  {
    f32x4 acc[4] = {};
#pragma unroll
    for (int kk = 0; kk < 2; ++kk) {
      short8 af = *(const short8*)&GMb[16 * w + r][kk * 32 + hi * 8];
#pragma unroll
      for (int j = 0; j < 4; ++j) {
        short8 bg = *(const short8*)&xdsT[16 * j + r][kk * 32 + hi * 8];
        acc[j] = __builtin_amdgcn_mfma_f32_16x16x32_bf16(af, bg, acc[j], 0, 0, 0);
      }
    }
#pragma unroll
    for (int j = 0; j < 4; ++j)
#pragma unroll
      for (int q = 0; q < 4; ++q) {
        int ll = 16 * w + hi * 4 + q, pp = 16 * j + r;
        size_t idx = (size_t)(row0 + ll) * DIN + h * PP + pp;
        y[idx] = f2b(acc[j][q] + b2f(xsp[idx]) * Dh);
      }
  }
  {
    f32x4 acc[8] = {};
#pragma unroll
    for (int kk = 0; kk < 2; ++kk) {
      short8 af = *(const short8*)&xdsT[16 * w + r][kk * 32 + hi * 8];
#pragma unroll
      for (int j = 0; j < 8; ++j) {
        short8 bg = *(const short8*)&BdT[16 * j + r][kk * 32 + hi * 8];
        acc[j] = __builtin_amdgcn_mfma_f32_16x16x32_bf16(af, bg, acc[j], 0, 0, 0);
      }
    }
    size_t sb = ((size_t)(b * NC + c) * HH + h) * (PP * NSD);
#pragma unroll
    for (int j = 0; j < 8; ++j)
#pragma unroll
      for (int q = 0; q < 4; ++q) {
        int pp = 16 * w + hi * 4 + q, nn = 16 * j + r;
        states[sb + (size_t)pp * NSD + nn] = f2b(acc[j][q]);
      }
  }
}

// ---------------------------------------------------------------------------
// Inter-chunk sequential scan, in place (bf16 storage, fp32 carry).
// Per-chunk decay factors preloaded to LDS (removes 64 dependent scalar
// loads + exp from the sequential chain). 8 contig elems/thread + prefetch.
// ---------------------------------------------------------------------------
__global__ __launch_bounds__(256) void scan(bf16* __restrict__ states,
                                            const float* __restrict__ cumA) {
  const int q = blockIdx.x, h = blockIdx.y, b = blockIdx.z;
  const int t = threadIdx.x;
  __shared__ float tots[NC];
  if (t < NC)
    tots[t] = expf(cumA[((size_t)(b * HH + h) * NC + t) * CHK + CHK - 1]);
  __syncthreads();
  const int off = q * 2048 + t * 8;
  const size_t cstride = (size_t)HH * PP * NSD;
  size_t base = ((size_t)(b * NC) * HH + h) * (PP * NSD) + off;
  float S[8] = {};
  uint4 nv = *(const uint4*)&states[base];
  for (int c = 0; c < NC; ++c) {
    uint4 cv = nv;
    if (c + 1 < NC) nv = *(const uint4*)&states[base + cstride];
    float tot = tots[c];
    const bf16* pin = (const bf16*)&cv;
    short8 sv;
#pragma unroll
    for (int i = 0; i < 8; ++i) {
      float cs = b2f(pin[i]);
      sv[i] = f2bs(S[i]);
      S[i] = S[i] * tot + cs;
    }
    *(short8*)&states[base] = sv;
    base += cstride;
  }
}

// ---------------------------------------------------------------------------
// Y_off[l][p] = dot(C[l,:], S[p,:]) — MFMA; y += Y_off*exp(cA).
// (D-term moved into ssd_chunk; xs stream dropped.)
// ---------------------------------------------------------------------------
__global__ __launch_bounds__(256) void yoff(
    const bf16* __restrict__ Cb, const bf16* __restrict__ states,
    const float* __restrict__ cumA, bf16* __restrict__ y) {
  const int h = blockIdx.x, c = blockIdx.y, b = blockIdx.z;
  const int row0 = (b * NC + c) * CHK;
  __shared__ short Csh[64][136];
  __shared__ short Ssh[64][136];
  __shared__ float dcy[CHK];
  const int t = threadIdx.x;
  const int lane = t & 63, w = t >> 6;
  if (t < CHK) dcy[t] = expf(cumA[((size_t)(b * HH + h) * NC + c) * CHK + t]);
  const size_t sbase = ((size_t)(b * NC + c) * HH + h) * (PP * NSD);
#pragma unroll
  for (int i = 0; i < 4; ++i) {
    int f = t + i * 256;
    int rr = f >> 4, n0 = (f & 15) * 8;
    *(uint4*)&Csh[rr][n0] = *(const uint4*)&Cb[(size_t)(row0 + rr) * NSD + n0];
    *(uint4*)&Ssh[rr][n0] = *(const uint4*)&states[sbase + (size_t)rr * NSD + n0];
  }
  __syncthreads();
  f32x4 acc[4] = {};
  const int r = lane & 15, hi = lane >> 4;
#pragma unroll
  for (int kk = 0; kk < 4; ++kk) {
    short8 af = *(const short8*)&Csh[16 * w + r][kk * 32 + hi * 8];
#pragma unroll
    for (int j = 0; j < 4; ++j) {
      short8 bg = *(const short8*)&Ssh[16 * j + r][kk * 32 + hi * 8];
      acc[j] = __builtin_amdgcn_mfma_f32_16x16x32_bf16(af, bg, acc[j], 0, 0, 0);
    }
  }
#pragma unroll
  for (int j = 0; j < 4; ++j)
#pragma unroll
    for (int q = 0; q < 4; ++q) {
      int ll = 16 * w + hi * 4 + q, pp = 16 * j + r;
      size_t idx = (size_t)(row0 + ll) * DIN + h * PP + pp;
      y[idx] = f2b(b2f(y[idx]) + acc[j][q] * dcy[ll]);
    }
}

// ---------------------------------------------------------------------------
// yz = y * silu(z); RMS-normalize over d_inner; scale; bf16 out. Vectorized.
// ---------------------------------------------------------------------------
__global__ __launch_bounds__(256) void gatenorm(const bf16* __restrict__ y,
                                                const bf16* __restrict__ zb,
                                                const float* __restrict__ nsc,
                                                bf16* __restrict__ outn) {
  const int row = blockIdx.x, t = threadIdx.x;
  const int ch = t * 8;
  uint4 yv4 = *(const uint4*)&y [(size_t)row * DIN + ch];
  uint4 zv4 = *(const uint4*)&zb[(size_t)row * DIN + ch];
  const bf16* yp = (const bf16*)&yv4;
  const bf16* zp = (const bf16*)&zv4;
  float v[8];
  float ss = 0.f;
#pragma unroll
  for (int i = 0; i < 8; ++i) {
    float z  = b2f(zp[i]);
    float g  = b2f(yp[i]) * z / (1.f + expf(-z));
    v[i] = g;
    ss += g * g;
  }
#pragma unroll
  for (int off = 32; off > 0; off >>= 1) ss += __shfl_down(ss, off, 64);
  __shared__ float red[4];
  if ((t & 63) == 0) red[t >> 6] = ss;
  __syncthreads();
  float tot = red[0] + red[1] + red[2] + red[3];
  float r = rsqrtf(tot * (1.f / DIN) + 1e-6f);
  short8 o;
#pragma unroll
  for (int i = 0; i < 8; ++i) o[i] = f2bs(v[i] * r * nsc[ch + i]);
  *(short8*)&outn[(size_t)row * DIN + ch] = o;
}

// ---------------------------------------------------------------------------
extern "C" void kernel_launch(void* const* d_in, const int* in_sizes, int n_in,
                              void* d_out, int out_size, void* d_ws, size_t ws_size,
                              hipStream_t stream) {
  const float* x     = (const float*)d_in[0];
  const float* inw   = (const float*)d_in[1];
  const float* convw = (const float*)d_in[2];
  const float* convb = (const float*)d_in[3];
  const float* dtb   = (const float*)d_in[4];
  const float* alog  = (const float*)d_in[5];
  const float* Dp    = (const float*)d_in[6];
  const float* nsc   = (const float*)d_in[7];
  const float* outw  = (const float*)d_in[8];
  float* out = (float*)d_out;

  // workspace layout — ~209 MB total (bf16 intermediates, aliased reuse)
  char* p = (char*)d_ws;
  bf16*  zb     = (bf16*)p;  p += (size_t)ROWS * DIN * 2;          //  33.6 MB
  bf16*  xbcb   = (bf16*)p;  p += (size_t)ROWS * CONVD * 2;        //  37.7 MB
  bf16*  y      = xbcb;      // reuse: conv consumes xbcb before y is written
  float* dtraw  = (float*)p; p += (size_t)ROWS * HH * 4;           //   1.0 MB
  bf16*  xs     = (bf16*)p;  p += (size_t)ROWS * DIN * 2;          //  33.6 MB
  bf16*  states = (bf16*)p;  p += (size_t)BB * NC * HH * PP * NSD * 2; // 67.1 MB
  bf16*  normb  = states;    // reuse: yoff consumes states before norm written
  bf16*  Bb     = (bf16*)p;  p += (size_t)ROWS * NSD * 2;          //   2.1 MB
  bf16*  Cb     = (bf16*)p;  p += (size_t)ROWS * NSD * 2;          //   2.1 MB
  float* dtv    = (float*)p; p += (size_t)ROWS * HH * 4;           //   1.0 MB
  float* dtA    = (float*)p; p += (size_t)ROWS * HH * 4;           //   1.0 MB
  float* cumA   = (float*)p; p += (size_t)BB * HH * NC * CHK * 4;  //   1.0 MB
  float* G      = (float*)p; p += (size_t)BB * NC * CHK * CHK * 4; //   2.1 MB
  bf16*  xb     = (bf16*)p;  p += (size_t)ROWS * DM * 2;           //  16.8 MB
  bf16*  BtIn   = (bf16*)p;  p += (size_t)NPAD * DM * 2;           //   9.2 MB
  bf16*  BtOut  = xb;        // reuse: xb dead after in_proj GEMM

  // 0a. x -> bf16
  convert_bf16<<<(ROWS * DM / 4 + 255) / 256, 256, 0, stream>>>(x, xb, ROWS * DM / 4);
  // 0b. in_proj_w [DM][DPROJ] -> BtIn bf16 [NPAD][DM]
  transpose_w<<<dim3(NPAD / 32, DM / 32), 256, 0, stream>>>(inw, BtIn, DM, DPROJ);
  // 1. in_proj GEMM (MFMA 128x128, single-barrier pipeline, split outputs)
  gemm_mfma<0, 4><<<dim3(NPAD / 128, ROWS / 128), 256, 0, stream>>>(
      (const short*)xb, (const short*)BtIn, DM, zb, xbcb, dtraw, nullptr);
  // 0c. out_proj_w [DIN][DM] -> BtOut bf16 [DM][DIN]  (into dead xb region)
  transpose_w<<<dim3(DM / 32, DIN / 32), 256, 0, stream>>>(outw, BtOut, DIN, DM);
  // 2. conv + activations + splits (bf16 B/C)
  conv_act<<<ROWS, 256, 0, stream>>>(xbcb, dtraw, convw, convb, dtb, alog,
                                     xs, Bb, Cb, dtv, dtA);
  // 3. G = C B^T per chunk (MFMA)
  gmat<<<dim3(NC, BB), 256, 0, stream>>>(Bb, Cb, G);
  // 4. Y_diag + D-term + chunk states per (b,c,h) (MFMA)
  ssd_chunk<<<dim3(HH, NC, BB), 256, 0, stream>>>(G, xs, Bb, dtv, dtA, Dp,
                                                  y, states, cumA);
  // 5. inter-chunk scan (in place, LDS-preloaded decay factors)
  scan<<<dim3(4, HH, BB), 256, 0, stream>>>(states, cumA);
  // 6. Y_off (MFMA; D-term already applied)
  yoff<<<dim3(HH, NC, BB), 256, 0, stream>>>(Cb, states, cumA, y);
  // 7. gate + RMSNorm (normed overwrites states region)
  gatenorm<<<ROWS, 256, 0, stream>>>(y, zb, nsc, normb);
  // 8. out_proj GEMM (MFMA 64x128, single-barrier pipeline, fp32 out)
  gemm_mfma<1, 2><<<dim3(DM / 128, ROWS / 64), 256, 0, stream>>>(
      (const short*)normb, (const short*)BtOut, DIN, nullptr, nullptr, nullptr, out);

  (void)in_sizes; (void)n_in; (void)out_size; (void)ws_size;
}

// Round 12
// 335.359 us; speedup vs baseline: 1.0496x; 1.0049x over previous
//
#include <hip/hip_runtime.h>
#include <hip/hip_bf16.h>
#include <math.h>

typedef __hip_bfloat16 bf16;
typedef __attribute__((ext_vector_type(8))) short short8;
typedef __attribute__((ext_vector_type(4))) float f32x4;

constexpr int BB    = 2;      // batch
constexpr int LL    = 4096;   // seq len
constexpr int DM    = 1024;   // d_model
constexpr int DIN   = 2048;   // d_inner
constexpr int HH    = 32;     // n_heads
constexpr int PP    = 64;     // head_dim
constexpr int NSD   = 128;    // d_state
constexpr int CONVD = 2304;   // d_inner + 2*d_state
constexpr int DPROJ = 4384;   // 2*d_inner + 2*d_state + n_heads
constexpr int NPAD  = 4480;   // DPROJ padded to 35*128
constexpr int CHK   = 64;     // chunk size
constexpr int NC    = 64;     // chunks per batch (L/CHK)
constexpr int ROWS  = BB * LL; // 8192

__device__ __forceinline__ float b2f(bf16 v) { return __bfloat162float(v); }
__device__ __forceinline__ bf16  f2b(float f) { return __float2bfloat16(f); }
__device__ __forceinline__ short f2bs(float f) {
  bf16 b = f2b(f);
  return *reinterpret_cast<short*>(&b);
}
// async global->LDS, 16B per lane; LDS dest = base + lane*16 (wave-uniform base)
__device__ __forceinline__ void gload16(const short* g, short* l) {
  __builtin_amdgcn_global_load_lds(
      (const __attribute__((address_space(1))) void*)g,
      (__attribute__((address_space(3))) void*)l, 16, 0, 0);
}
template <int N> __device__ __forceinline__ void waitvm() {
  if constexpr (N == 0)      asm volatile("s_waitcnt vmcnt(0)" ::: "memory");
  else if constexpr (N == 3) asm volatile("s_waitcnt vmcnt(3)" ::: "memory");
  else                       asm volatile("s_waitcnt vmcnt(4)" ::: "memory");
}
__device__ __forceinline__ void barrier_raw() {
  asm volatile("s_barrier" ::: "memory");
}

// ---------------------------------------------------------------------------
// fp32 -> bf16 elementwise. 4 elems/thread.
// ---------------------------------------------------------------------------
__global__ __launch_bounds__(256) void convert_bf16(const float* __restrict__ in,
                                                    bf16* __restrict__ outp, int n4) {
  int i = blockIdx.x * 256 + threadIdx.x;
  if (i >= n4) return;
  float4 v = *(const float4*)&in[(size_t)i * 4];
  bf16* p = &outp[(size_t)i * 4];
  p[0] = f2b(v.x); p[1] = f2b(v.y); p[2] = f2b(v.z); p[3] = f2b(v.w);
}

// ---------------------------------------------------------------------------
// Transpose + convert: W fp32 [K][N] row-major -> Bt bf16 [Npad][K] row-major.
// ---------------------------------------------------------------------------
__global__ __launch_bounds__(256) void transpose_w(const float* __restrict__ W,
                                                   bf16* __restrict__ Bt,
                                                   int K, int N) {
  __shared__ float Tl[32][33];
  const int n0 = blockIdx.x * 32, k0 = blockIdx.y * 32;
  const int t = threadIdx.x;
  {
    const int kk = t >> 3, nn4 = (t & 7) * 4;
#pragma unroll
    for (int j = 0; j < 4; ++j) {
      int n = n0 + nn4 + j;
      Tl[kk][nn4 + j] = (n < N) ? W[(size_t)(k0 + kk) * N + n] : 0.f;
    }
  }
  __syncthreads();
  {
    const int nn = t >> 3, kk4 = (t & 7) * 4;
#pragma unroll
    for (int j = 0; j < 4; ++j)
      Bt[(size_t)(n0 + nn) * K + k0 + kk4 + j] = f2b(Tl[kk4 + j][nn]);
  }
}

// ---------------------------------------------------------------------------
// bf16 MFMA GEMM, (MI*32)x128 tile, BK=32, 4 waves (2x2), MI x 4 16x16x32
// tiles/wave. 3-buffer LDS, SINGLE barrier per K-step (R8, proven 109 us):
//   iter ti:  STAGE(ti+1 -> buf[(ti+1)%3]) -> vmcnt(NL) -> s_barrier
//             -> ds_read + MFMA on buf[ti%3]
// Pre-swizzled global source + swizzled read (conflict-free). Bijective XCD
// swizzle. MODE 0: split store zb/xbcb/dtraw. MODE 1: fp32 C. Both MI=4.
// ---------------------------------------------------------------------------
template <int MODE, int MI>
__global__ __launch_bounds__(256) void gemm_mfma(
    const short* __restrict__ A, const short* __restrict__ Bt, int K,
    bf16* __restrict__ zb, bf16* __restrict__ xbcb,
    float* __restrict__ dtraw, float* __restrict__ Cout) {
  constexpr int MROWS = MI * 32;        // A-tile rows (128 or 64)
  constexpr int NL = (MI == 4) ? 4 : 3; // gloads per wave per tile
  constexpr int GX = (MODE == 0) ? NPAD / 128 : DM / 128;   // grid x
  constexpr int GY = ROWS / MROWS;                          // grid y
  constexpr int NWG = GX * GY;          // 2240 / 512, both % 8 == 0
  constexpr int CPX = NWG / 8;
  __shared__ short Asl[3][MROWS * 32];
  __shared__ short Bsl[3][128 * 32];
  const int t = threadIdx.x;
  const int l = t & 63;
  const int w = t >> 6;
  const int wr = w >> 1, wc = w & 1;

  int bid = blockIdx.y * GX + blockIdx.x;
  bid = (bid & 7) * CPX + (bid >> 3);
  const int m0 = (bid / GX) * MROWS;
  const int n0 = (bid % GX) * 128;

  const int srow = l >> 2;
  const int sk   = (((l & 3) - ((l >> 3) & 3)) & 3) * 8;  // shorts
  const short* gA0 = &A [(size_t)(m0 + w * 16 + srow) * K + sk];
  const short* gA1 = (MI == 4) ? &A[(size_t)(m0 + (4 + w) * 16 + srow) * K + sk]
                               : gA0;
  const short* gB0 = &Bt[(size_t)(n0 + w * 16 + srow) * K + sk];
  const short* gB1 = &Bt[(size_t)(n0 + (4 + w) * 16 + srow) * K + sk];
  const int ldsW0 = (w * 16) * 32, ldsW1 = ((4 + w) * 16) * 32;

  auto STAGE = [&](int buf) {
    gload16(gA0, &Asl[buf][ldsW0]);
    if constexpr (MI == 4) gload16(gA1, &Asl[buf][ldsW1]);
    gload16(gB0, &Bsl[buf][ldsW0]);
    gload16(gB1, &Bsl[buf][ldsW1]);
    gA0 += 32; if constexpr (MI == 4) gA1 += 32;
    gB0 += 32; gB1 += 32;
  };

  const int fr = l & 15;
  const int s2 = (((l >> 4) + ((fr >> 1) & 3)) & 3) * 8;
  const int aoff = (wr * (MI * 16) + fr) * 32 + s2;
  const int boff = (wc * 64 + fr) * 32 + s2;

  f32x4 acc[MI][4] = {};
  const int nt = K >> 5;

  STAGE(0);

  for (int ti = 0; ti < nt; ++ti) {
    const int cur = ti % 3;
    if (ti + 1 < nt) {
      STAGE((ti + 1) % 3);
      waitvm<NL>();
    } else {
      waitvm<0>();
    }
    barrier_raw();
    short8 af[MI], bg[4];
#pragma unroll
    for (int i = 0; i < MI; ++i) af[i] = *(const short8*)&Asl[cur][aoff + i * 512];
#pragma unroll
    for (int j = 0; j < 4; ++j)  bg[j] = *(const short8*)&Bsl[cur][boff + j * 512];
#pragma unroll
    for (int i = 0; i < MI; ++i)
#pragma unroll
      for (int j = 0; j < 4; ++j)
        acc[i][j] = __builtin_amdgcn_mfma_f32_16x16x32_bf16(af[i], bg[j],
                                                            acc[i][j], 0, 0, 0);
  }
#pragma unroll
  for (int i = 0; i < MI; ++i) {
#pragma unroll
    for (int j = 0; j < 4; ++j) {
      int gcol = n0 + wc * 64 + j * 16 + (l & 15);
      int grow0 = m0 + wr * (MI * 16) + i * 16 + (l >> 4) * 4;
#pragma unroll
      for (int q = 0; q < 4; ++q) {
        float v = acc[i][j][q];
        int grow = grow0 + q;
        if constexpr (MODE == 0) {
          if (gcol < DIN) {
            zb[(size_t)grow * DIN + gcol] = f2b(v);
          } else if (gcol < DIN + CONVD) {
            xbcb[(size_t)grow * CONVD + (gcol - DIN)] = f2b(v);
          } else if (gcol < DPROJ) {
            dtraw[(size_t)grow * HH + (gcol - DIN - CONVD)] = v;
          }
        } else {
          Cout[(size_t)grow * DM + gcol] = v;
        }
      }
    }
  }
}

// ---------------------------------------------------------------------------
// Depthwise causal conv1d (k=4) + bias + silu + splits; dt softplus; dtA.
// ---------------------------------------------------------------------------
__global__ __launch_bounds__(256) void conv_act(
    const bf16* __restrict__ xbc, const float* __restrict__ dtraw,
    const float* __restrict__ convw, const float* __restrict__ convb,
    const float* __restrict__ dtb, const float* __restrict__ alog,
    bf16* __restrict__ xs, bf16* __restrict__ Bb, bf16* __restrict__ Cb,
    float* __restrict__ dtv, float* __restrict__ dtA) {
  const int row = blockIdx.x;
  const int l   = row & (LL - 1);
  const int t   = threadIdx.x;
  if (t < HH) {
    float raw = dtraw[(size_t)row * HH + t] + dtb[t];
    float dt  = (raw > 20.f) ? raw : log1pf(expf(raw));
    dtv[(size_t)row * HH + t] = dt;
    dtA[(size_t)row * HH + t] = -expf(alog[t]) * dt;
  }
  for (int ch = t * 8; ch < CONVD; ch += 2048) {
    float acc[8];
#pragma unroll
    for (int j = 0; j < 8; ++j) acc[j] = convb[ch + j];
#pragma unroll
    for (int k = 0; k < 4; ++k) {
      if (l - 3 + k >= 0) {
        uint4 v = *(const uint4*)&xbc[(size_t)(row - 3 + k) * CONVD + ch];
        const bf16* pv = (const bf16*)&v;
        const float* wp = &convw[k * CONVD + ch];
#pragma unroll
        for (int j = 0; j < 8; ++j) acc[j] += b2f(pv[j]) * wp[j];
      }
    }
    short8 sv;
#pragma unroll
    for (int j = 0; j < 8; ++j) {
      float s = acc[j] / (1.f + expf(-acc[j])); // silu
      sv[j] = f2bs(s);
    }
    if (ch < DIN) {
      *(short8*)&xs[(size_t)row * DIN + ch] = sv;
    } else if (ch < DIN + NSD) {
      *(short8*)&Bb[(size_t)row * NSD + (ch - DIN)] = sv;
    } else {
      *(short8*)&Cb[(size_t)row * NSD + (ch - DIN - NSD)] = sv;
    }
  }
}

// ---------------------------------------------------------------------------
// G[b,c,l,s] = dot(C[l,:], B[s,:]) — MFMA. One block per (b,c).
// ---------------------------------------------------------------------------
__global__ __launch_bounds__(256) void gmat(const bf16* __restrict__ Bb,
                                            const bf16* __restrict__ Cb,
                                            float* __restrict__ G) {
  const int c = blockIdx.x, b = blockIdx.y;
  const int row0 = (b * NC + c) * CHK;
  __shared__ short Csh[64][136];
  __shared__ short Bsh[64][136];
  const int t = threadIdx.x;
  const int lane = t & 63, w = t >> 6;
#pragma unroll
  for (int i = 0; i < 4; ++i) {
    int f = t + i * 256;
    int rr = f >> 4, n0 = (f & 15) * 8;
    *(uint4*)&Csh[rr][n0] = *(const uint4*)&Cb[(size_t)(row0 + rr) * NSD + n0];
    *(uint4*)&Bsh[rr][n0] = *(const uint4*)&Bb[(size_t)(row0 + rr) * NSD + n0];
  }
  __syncthreads();
  f32x4 acc[4] = {};
  const int r = lane & 15, hi = lane >> 4;
#pragma unroll
  for (int kk = 0; kk < 4; ++kk) {
    short8 af = *(const short8*)&Csh[16 * w + r][kk * 32 + hi * 8];
#pragma unroll
    for (int j = 0; j < 4; ++j) {
      short8 bg = *(const short8*)&Bsh[16 * j + r][kk * 32 + hi * 8];
      acc[j] = __builtin_amdgcn_mfma_f32_16x16x32_bf16(af, bg, acc[j], 0, 0, 0);
    }
  }
#pragma unroll
  for (int j = 0; j < 4; ++j)
#pragma unroll
    for (int q = 0; q < 4; ++q) {
      int ll = 16 * w + hi * 4 + q, ss = 16 * j + r;
      G[((size_t)(b * NC + c) * CHK + ll) * CHK + ss] = acc[j][q];
    }
}

// ---------------------------------------------------------------------------
// Per (b,c,h): cumsum(dtA) via Kogge-Stone; Y_diag (MFMA) + D-term fused;
// states (MFMA). y = Y_diag + xs*D (exact xs re-read, L2-hot).
// ---------------------------------------------------------------------------
__global__ __launch_bounds__(256) void ssd_chunk(
    const float* __restrict__ G, const bf16* __restrict__ xsp,
    const bf16* __restrict__ Bb, const float* __restrict__ dtv,
    const float* __restrict__ dtA, const float* __restrict__ Dp,
    bf16* __restrict__ y, bf16* __restrict__ states, float* __restrict__ cumA) {
  const int h = blockIdx.x, c = blockIdx.y, b = blockIdx.z;
  const int row0 = (b * NC + c) * CHK;
  __shared__ short GMb[64][72];
  __shared__ short xdsT[64][72];
  __shared__ short BdT[128][72];
  __shared__ float cA[CHK], dec[CHK], sdt[CHK];
  const int t = threadIdx.x;
  const int lane = t & 63, w = t >> 6;
  if (t < CHK) {
    sdt[t] = dtv[(size_t)(row0 + t) * HH + h];
    float v = dtA[(size_t)(row0 + t) * HH + h];
#pragma unroll
    for (int o = 1; o < 64; o <<= 1) {
      float u = __shfl_up(v, o, 64);
      if (t >= o) v += u;
    }
    cA[t] = v;
  }
  __syncthreads();
  if (t < CHK) {
    dec[t] = expf(cA[CHK - 1] - cA[t]);
    cumA[((size_t)(b * HH + h) * NC + c) * CHK + t] = cA[t];
  }
#pragma unroll
  for (int i = 0; i < 2; ++i) {
    int f = t + i * 256;
    int ll = f >> 3, p0 = (f & 7) * 8;
    uint4 v = *(const uint4*)&xsp[(size_t)(row0 + ll) * DIN + h * PP + p0];
    const bf16* pv = (const bf16*)&v;
    float dtl = sdt[ll];
#pragma unroll
    for (int j = 0; j < 8; ++j) xdsT[p0 + j][ll] = f2bs(b2f(pv[j]) * dtl);
  }
#pragma unroll
  for (int i = 0; i < 4; ++i) {
    int f = t + i * 256;
    int ll = f >> 4, s0 = (f & 15) * 4;
    float4 g = *(const float4*)&G[((size_t)(b * NC + c) * CHK + ll) * CHK + s0];
    float ca = cA[ll];
    GMb[ll][s0 + 0] = f2bs((s0 + 0 <= ll) ? g.x * expf(ca - cA[s0 + 0]) : 0.f);
    GMb[ll][s0 + 1] = f2bs((s0 + 1 <= ll) ? g.y * expf(ca - cA[s0 + 1]) : 0.f);
    GMb[ll][s0 + 2] = f2bs((s0 + 2 <= ll) ? g.z * expf(ca - cA[s0 + 2]) : 0.f);
    GMb[ll][s0 + 3] = f2bs((s0 + 3 <= ll) ? g.w * expf(ca - cA[s0 + 3]) : 0.f);
  }
  __syncthreads();
#pragma unroll
  for (int i = 0; i < 4; ++i) {
    int f = t + i * 256;
    int ll = f >> 4, n0 = (f & 15) * 8;
    uint4 v = *(const uint4*)&Bb[(size_t)(row0 + ll) * NSD + n0];
    const bf16* pv = (const bf16*)&v;
    float dl = dec[ll];
#pragma unroll
    for (int j = 0; j < 8; ++j) BdT[n0 + j][ll] = f2bs(b2f(pv[j]) * dl);
  }
  __syncthreads();
  const int r = lane & 15, hi = lane >> 4;
  const float Dh = Dp[h];
  {
    f32x4 acc[4] = {};
#pragma unroll
    for (int kk = 0; kk < 2; ++kk) {
      short8 af = *(const short8*)&GMb[16 * w + r][kk * 32 + hi * 8];
#pragma unroll
      for (int j = 0; j < 4; ++j) {
        short8 bg = *(const short8*)&xdsT[16 * j + r][kk * 32 + hi * 8];
        acc[j] = __builtin_amdgcn_mfma_f32_16x16x32_bf16(af, bg, acc[j], 0, 0, 0);
      }
    }
#pragma unroll
    for (int j = 0; j < 4; ++j)
#pragma unroll
      for (int q = 0; q < 4; ++q) {
        int ll = 16 * w + hi * 4 + q, pp = 16 * j + r;
        size_t idx = (size_t)(row0 + ll) * DIN + h * PP + pp;
        y[idx] = f2b(acc[j][q] + b2f(xsp[idx]) * Dh);
      }
  }
  {
    f32x4 acc[8] = {};
#pragma unroll
    for (int kk = 0; kk < 2; ++kk) {
      short8 af = *(const short8*)&xdsT[16 * w + r][kk * 32 + hi * 8];
#pragma unroll
      for (int j = 0; j < 8; ++j) {
        short8 bg = *(const short8*)&BdT[16 * j + r][kk * 32 + hi * 8];
        acc[j] = __builtin_amdgcn_mfma_f32_16x16x32_bf16(af, bg, acc[j], 0, 0, 0);
      }
    }
    size_t sb = ((size_t)(b * NC + c) * HH + h) * (PP * NSD);
#pragma unroll
    for (int j = 0; j < 8; ++j)
#pragma unroll
      for (int q = 0; q < 4; ++q) {
        int pp = 16 * w + hi * 4 + q, nn = 16 * j + r;
        states[sb + (size_t)pp * NSD + nn] = f2b(acc[j][q]);
      }
  }
}

// ---------------------------------------------------------------------------
// Inter-chunk sequential scan, in place (bf16 storage, fp32 carry).
// LDS-preloaded decay factors + 2-DEEP register prefetch (covers ~2x HBM
// latency on the 64-long sequential chain; stores trail reads by >=1 chunk).
// ---------------------------------------------------------------------------
__global__ __launch_bounds__(256) void scan(bf16* __restrict__ states,
                                            const float* __restrict__ cumA) {
  const int q = blockIdx.x, h = blockIdx.y, b = blockIdx.z;
  const int t = threadIdx.x;
  __shared__ float tots[NC];
  if (t < NC)
    tots[t] = expf(cumA[((size_t)(b * HH + h) * NC + t) * CHK + CHK - 1]);
  __syncthreads();
  const int off = q * 2048 + t * 8;
  const size_t cstride = (size_t)HH * PP * NSD;
  size_t base = ((size_t)(b * NC) * HH + h) * (PP * NSD) + off;
  float S[8] = {};
  uint4 v0 = *(const uint4*)&states[base];
  uint4 v1 = *(const uint4*)&states[base + cstride];
  for (int c = 0; c < NC; ++c) {
    uint4 cv = v0;
    v0 = v1;
    if (c + 2 < NC) v1 = *(const uint4*)&states[base + 2 * cstride];
    float tot = tots[c];
    const bf16* pin = (const bf16*)&cv;
    short8 sv;
#pragma unroll
    for (int i = 0; i < 8; ++i) {
      float cs = b2f(pin[i]);
      sv[i] = f2bs(S[i]);
      S[i] = S[i] * tot + cs;
    }
    *(short8*)&states[base] = sv;
    base += cstride;
  }
}

// ---------------------------------------------------------------------------
// Y_off[l][p] = dot(C[l,:], S[p,:]) — MFMA; y += Y_off*exp(cA).
// ---------------------------------------------------------------------------
__global__ __launch_bounds__(256) void yoff(
    const bf16* __restrict__ Cb, const bf16* __restrict__ states,
    const float* __restrict__ cumA, bf16* __restrict__ y) {
  const int h = blockIdx.x, c = blockIdx.y, b = blockIdx.z;
  const int row0 = (b * NC + c) * CHK;
  __shared__ short Csh[64][136];
  __shared__ short Ssh[64][136];
  __shared__ float dcy[CHK];
  const int t = threadIdx.x;
  const int lane = t & 63, w = t >> 6;
  if (t < CHK) dcy[t] = expf(cumA[((size_t)(b * HH + h) * NC + c) * CHK + t]);
  const size_t sbase = ((size_t)(b * NC + c) * HH + h) * (PP * NSD);
#pragma unroll
  for (int i = 0; i < 4; ++i) {
    int f = t + i * 256;
    int rr = f >> 4, n0 = (f & 15) * 8;
    *(uint4*)&Csh[rr][n0] = *(const uint4*)&Cb[(size_t)(row0 + rr) * NSD + n0];
    *(uint4*)&Ssh[rr][n0] = *(const uint4*)&states[sbase + (size_t)rr * NSD + n0];
  }
  __syncthreads();
  f32x4 acc[4] = {};
  const int r = lane & 15, hi = lane >> 4;
#pragma unroll
  for (int kk = 0; kk < 4; ++kk) {
    short8 af = *(const short8*)&Csh[16 * w + r][kk * 32 + hi * 8];
#pragma unroll
    for (int j = 0; j < 4; ++j) {
      short8 bg = *(const short8*)&Ssh[16 * j + r][kk * 32 + hi * 8];
      acc[j] = __builtin_amdgcn_mfma_f32_16x16x32_bf16(af, bg, acc[j], 0, 0, 0);
    }
  }
#pragma unroll
  for (int j = 0; j < 4; ++j)
#pragma unroll
    for (int q = 0; q < 4; ++q) {
      int ll = 16 * w + hi * 4 + q, pp = 16 * j + r;
      size_t idx = (size_t)(row0 + ll) * DIN + h * PP + pp;
      y[idx] = f2b(b2f(y[idx]) + acc[j][q] * dcy[ll]);
    }
}

// ---------------------------------------------------------------------------
// yz = y * silu(z); RMS-normalize over d_inner; scale; bf16 out. Vectorized.
// ---------------------------------------------------------------------------
__global__ __launch_bounds__(256) void gatenorm(const bf16* __restrict__ y,
                                                const bf16* __restrict__ zb,
                                                const float* __restrict__ nsc,
                                                bf16* __restrict__ outn) {
  const int row = blockIdx.x, t = threadIdx.x;
  const int ch = t * 8;
  uint4 yv4 = *(const uint4*)&y [(size_t)row * DIN + ch];
  uint4 zv4 = *(const uint4*)&zb[(size_t)row * DIN + ch];
  const bf16* yp = (const bf16*)&yv4;
  const bf16* zp = (const bf16*)&zv4;
  float v[8];
  float ss = 0.f;
#pragma unroll
  for (int i = 0; i < 8; ++i) {
    float z  = b2f(zp[i]);
    float g  = b2f(yp[i]) * z / (1.f + expf(-z));
    v[i] = g;
    ss += g * g;
  }
#pragma unroll
  for (int off = 32; off > 0; off >>= 1) ss += __shfl_down(ss, off, 64);
  __shared__ float red[4];
  if ((t & 63) == 0) red[t >> 6] = ss;
  __syncthreads();
  float tot = red[0] + red[1] + red[2] + red[3];
  float r = rsqrtf(tot * (1.f / DIN) + 1e-6f);
  short8 o;
#pragma unroll
  for (int i = 0; i < 8; ++i) o[i] = f2bs(v[i] * r * nsc[ch + i]);
  *(short8*)&outn[(size_t)row * DIN + ch] = o;
}

// ---------------------------------------------------------------------------
extern "C" void kernel_launch(void* const* d_in, const int* in_sizes, int n_in,
                              void* d_out, int out_size, void* d_ws, size_t ws_size,
                              hipStream_t stream) {
  const float* x     = (const float*)d_in[0];
  const float* inw   = (const float*)d_in[1];
  const float* convw = (const float*)d_in[2];
  const float* convb = (const float*)d_in[3];
  const float* dtb   = (const float*)d_in[4];
  const float* alog  = (const float*)d_in[5];
  const float* Dp    = (const float*)d_in[6];
  const float* nsc   = (const float*)d_in[7];
  const float* outw  = (const float*)d_in[8];
  float* out = (float*)d_out;

  // workspace layout — ~209 MB total (bf16 intermediates, aliased reuse)
  char* p = (char*)d_ws;
  bf16*  zb     = (bf16*)p;  p += (size_t)ROWS * DIN * 2;          //  33.6 MB
  bf16*  xbcb   = (bf16*)p;  p += (size_t)ROWS * CONVD * 2;        //  37.7 MB
  bf16*  y      = xbcb;      // reuse: conv consumes xbcb before y is written
  float* dtraw  = (float*)p; p += (size_t)ROWS * HH * 4;           //   1.0 MB
  bf16*  xs     = (bf16*)p;  p += (size_t)ROWS * DIN * 2;          //  33.6 MB
  bf16*  states = (bf16*)p;  p += (size_t)BB * NC * HH * PP * NSD * 2; // 67.1 MB
  bf16*  normb  = states;    // reuse: yoff consumes states before norm written
  bf16*  Bb     = (bf16*)p;  p += (size_t)ROWS * NSD * 2;          //   2.1 MB
  bf16*  Cb     = (bf16*)p;  p += (size_t)ROWS * NSD * 2;          //   2.1 MB
  float* dtv    = (float*)p; p += (size_t)ROWS * HH * 4;           //   1.0 MB
  float* dtA    = (float*)p; p += (size_t)ROWS * HH * 4;           //   1.0 MB
  float* cumA   = (float*)p; p += (size_t)BB * HH * NC * CHK * 4;  //   1.0 MB
  float* G      = (float*)p; p += (size_t)BB * NC * CHK * CHK * 4; //   2.1 MB
  bf16*  xb     = (bf16*)p;  p += (size_t)ROWS * DM * 2;           //  16.8 MB
  bf16*  BtIn   = (bf16*)p;  p += (size_t)NPAD * DM * 2;           //   9.2 MB
  bf16*  BtOut  = xb;        // reuse: xb dead after in_proj GEMM

  // 0a. x -> bf16
  convert_bf16<<<(ROWS * DM / 4 + 255) / 256, 256, 0, stream>>>(x, xb, ROWS * DM / 4);
  // 0b. in_proj_w [DM][DPROJ] -> BtIn bf16 [NPAD][DM]
  transpose_w<<<dim3(NPAD / 32, DM / 32), 256, 0, stream>>>(inw, BtIn, DM, DPROJ);
  // 1. in_proj GEMM (MFMA 128x128, single-barrier pipeline, split outputs)
  gemm_mfma<0, 4><<<dim3(NPAD / 128, ROWS / 128), 256, 0, stream>>>(
      (const short*)xb, (const short*)BtIn, DM, zb, xbcb, dtraw, nullptr);
  // 0c. out_proj_w [DIN][DM] -> BtOut bf16 [DM][DIN]  (into dead xb region)
  transpose_w<<<dim3(DM / 32, DIN / 32), 256, 0, stream>>>(outw, BtOut, DIN, DM);
  // 2. conv + activations + splits (bf16 B/C)
  conv_act<<<ROWS, 256, 0, stream>>>(xbcb, dtraw, convw, convb, dtb, alog,
                                     xs, Bb, Cb, dtv, dtA);
  // 3. G = C B^T per chunk (MFMA)
  gmat<<<dim3(NC, BB), 256, 0, stream>>>(Bb, Cb, G);
  // 4. Y_diag + D-term + chunk states per (b,c,h) (MFMA)
  ssd_chunk<<<dim3(HH, NC, BB), 256, 0, stream>>>(G, xs, Bb, dtv, dtA, Dp,
                                                  y, states, cumA);
  // 5. inter-chunk scan (in place, 2-deep prefetch)
  scan<<<dim3(4, HH, BB), 256, 0, stream>>>(states, cumA);
  // 6. Y_off (MFMA; D-term already applied)
  yoff<<<dim3(HH, NC, BB), 256, 0, stream>>>(Cb, states, cumA, y);
  // 7. gate + RMSNorm (normed overwrites states region)
  gatenorm<<<ROWS, 256, 0, stream>>>(y, zb, nsc, normb);
  // 8. out_proj GEMM (MFMA 128x128, single-barrier pipeline, fp32 out)
  gemm_mfma<1, 4><<<dim3(DM / 128, ROWS / 128), 256, 0, stream>>>(
      (const short*)normb, (const short*)BtOut, DIN, nullptr, nullptr, nullptr, out);

  (void)in_sizes; (void)n_in; (void)out_size; (void)ws_size;
}

// Round 13
// 331.298 us; speedup vs baseline: 1.0624x; 1.0123x over previous
//
#include <hip/hip_runtime.h>
#include <hip/hip_bf16.h>
#include <math.h>

typedef __hip_bfloat16 bf16;
typedef __attribute__((ext_vector_type(8))) short short8;
typedef __attribute__((ext_vector_type(4))) float f32x4;

constexpr int BB    = 2;      // batch
constexpr int LL    = 4096;   // seq len
constexpr int DM    = 1024;   // d_model
constexpr int DIN   = 2048;   // d_inner
constexpr int HH    = 32;     // n_heads
constexpr int PP    = 64;     // head_dim
constexpr int NSD   = 128;    // d_state
constexpr int CONVD = 2304;   // d_inner + 2*d_state
constexpr int DPROJ = 4384;   // 2*d_inner + 2*d_state + n_heads
constexpr int NPAD  = 4480;   // DPROJ padded to 35*128
constexpr int CHK   = 64;     // chunk size
constexpr int NC    = 64;     // chunks per batch (L/CHK)
constexpr int ROWS  = BB * LL; // 8192

__device__ __forceinline__ float b2f(bf16 v) { return __bfloat162float(v); }
__device__ __forceinline__ bf16  f2b(float f) { return __float2bfloat16(f); }
__device__ __forceinline__ short f2bs(float f) {
  bf16 b = f2b(f);
  return *reinterpret_cast<short*>(&b);
}
// fast exp: v_exp_f32 (2^x) + 1 mul; ~2 ulp — below bf16 rounding everywhere used
__device__ __forceinline__ float fexp(float x) { return __expf(x); }
// async global->LDS, 16B per lane; LDS dest = base + lane*16 (wave-uniform base)
__device__ __forceinline__ void gload16(const short* g, short* l) {
  __builtin_amdgcn_global_load_lds(
      (const __attribute__((address_space(1))) void*)g,
      (__attribute__((address_space(3))) void*)l, 16, 0, 0);
}
template <int N> __device__ __forceinline__ void waitvm() {
  if constexpr (N == 0)      asm volatile("s_waitcnt vmcnt(0)" ::: "memory");
  else if constexpr (N == 3) asm volatile("s_waitcnt vmcnt(3)" ::: "memory");
  else                       asm volatile("s_waitcnt vmcnt(4)" ::: "memory");
}
__device__ __forceinline__ void barrier_raw() {
  asm volatile("s_barrier" ::: "memory");
}

// ---------------------------------------------------------------------------
// fp32 -> bf16 elementwise. 4 elems/thread.
// ---------------------------------------------------------------------------
__global__ __launch_bounds__(256) void convert_bf16(const float* __restrict__ in,
                                                    bf16* __restrict__ outp, int n4) {
  int i = blockIdx.x * 256 + threadIdx.x;
  if (i >= n4) return;
  float4 v = *(const float4*)&in[(size_t)i * 4];
  bf16* p = &outp[(size_t)i * 4];
  p[0] = f2b(v.x); p[1] = f2b(v.y); p[2] = f2b(v.z); p[3] = f2b(v.w);
}

// ---------------------------------------------------------------------------
// Transpose + convert: W fp32 [K][N] row-major -> Bt bf16 [Npad][K] row-major.
// ---------------------------------------------------------------------------
__global__ __launch_bounds__(256) void transpose_w(const float* __restrict__ W,
                                                   bf16* __restrict__ Bt,
                                                   int K, int N) {
  __shared__ float Tl[32][33];
  const int n0 = blockIdx.x * 32, k0 = blockIdx.y * 32;
  const int t = threadIdx.x;
  {
    const int kk = t >> 3, nn4 = (t & 7) * 4;
#pragma unroll
    for (int j = 0; j < 4; ++j) {
      int n = n0 + nn4 + j;
      Tl[kk][nn4 + j] = (n < N) ? W[(size_t)(k0 + kk) * N + n] : 0.f;
    }
  }
  __syncthreads();
  {
    const int nn = t >> 3, kk4 = (t & 7) * 4;
#pragma unroll
    for (int j = 0; j < 4; ++j)
      Bt[(size_t)(n0 + nn) * K + k0 + kk4 + j] = f2b(Tl[kk4 + j][nn]);
  }
}

// ---------------------------------------------------------------------------
// bf16 MFMA GEMM, (MI*32)x128 tile, BK=32, 4 waves (2x2), MI x 4 16x16x32
// tiles/wave. 3-buffer LDS, SINGLE barrier per K-step (proven 109 us).
// Pre-swizzled global source + swizzled read (conflict-free). Bijective XCD
// swizzle. MODE 0: split store zb/xbcb/dtraw. MODE 1: fp32 C. Both MI=4.
// ---------------------------------------------------------------------------
template <int MODE, int MI>
__global__ __launch_bounds__(256) void gemm_mfma(
    const short* __restrict__ A, const short* __restrict__ Bt, int K,
    bf16* __restrict__ zb, bf16* __restrict__ xbcb,
    float* __restrict__ dtraw, float* __restrict__ Cout) {
  constexpr int MROWS = MI * 32;
  constexpr int NL = (MI == 4) ? 4 : 3;
  constexpr int GX = (MODE == 0) ? NPAD / 128 : DM / 128;
  constexpr int GY = ROWS / MROWS;
  constexpr int NWG = GX * GY;
  constexpr int CPX = NWG / 8;
  __shared__ short Asl[3][MROWS * 32];
  __shared__ short Bsl[3][128 * 32];
  const int t = threadIdx.x;
  const int l = t & 63;
  const int w = t >> 6;
  const int wr = w >> 1, wc = w & 1;

  int bid = blockIdx.y * GX + blockIdx.x;
  bid = (bid & 7) * CPX + (bid >> 3);
  const int m0 = (bid / GX) * MROWS;
  const int n0 = (bid % GX) * 128;

  const int srow = l >> 2;
  const int sk   = (((l & 3) - ((l >> 3) & 3)) & 3) * 8;
  const short* gA0 = &A [(size_t)(m0 + w * 16 + srow) * K + sk];
  const short* gA1 = (MI == 4) ? &A[(size_t)(m0 + (4 + w) * 16 + srow) * K + sk]
                               : gA0;
  const short* gB0 = &Bt[(size_t)(n0 + w * 16 + srow) * K + sk];
  const short* gB1 = &Bt[(size_t)(n0 + (4 + w) * 16 + srow) * K + sk];
  const int ldsW0 = (w * 16) * 32, ldsW1 = ((4 + w) * 16) * 32;

  auto STAGE = [&](int buf) {
    gload16(gA0, &Asl[buf][ldsW0]);
    if constexpr (MI == 4) gload16(gA1, &Asl[buf][ldsW1]);
    gload16(gB0, &Bsl[buf][ldsW0]);
    gload16(gB1, &Bsl[buf][ldsW1]);
    gA0 += 32; if constexpr (MI == 4) gA1 += 32;
    gB0 += 32; gB1 += 32;
  };

  const int fr = l & 15;
  const int s2 = (((l >> 4) + ((fr >> 1) & 3)) & 3) * 8;
  const int aoff = (wr * (MI * 16) + fr) * 32 + s2;
  const int boff = (wc * 64 + fr) * 32 + s2;

  f32x4 acc[MI][4] = {};
  const int nt = K >> 5;

  STAGE(0);

  for (int ti = 0; ti < nt; ++ti) {
    const int cur = ti % 3;
    if (ti + 1 < nt) {
      STAGE((ti + 1) % 3);
      waitvm<NL>();
    } else {
      waitvm<0>();
    }
    barrier_raw();
    short8 af[MI], bg[4];
#pragma unroll
    for (int i = 0; i < MI; ++i) af[i] = *(const short8*)&Asl[cur][aoff + i * 512];
#pragma unroll
    for (int j = 0; j < 4; ++j)  bg[j] = *(const short8*)&Bsl[cur][boff + j * 512];
#pragma unroll
    for (int i = 0; i < MI; ++i)
#pragma unroll
      for (int j = 0; j < 4; ++j)
        acc[i][j] = __builtin_amdgcn_mfma_f32_16x16x32_bf16(af[i], bg[j],
                                                            acc[i][j], 0, 0, 0);
  }
#pragma unroll
  for (int i = 0; i < MI; ++i) {
#pragma unroll
    for (int j = 0; j < 4; ++j) {
      int gcol = n0 + wc * 64 + j * 16 + (l & 15);
      int grow0 = m0 + wr * (MI * 16) + i * 16 + (l >> 4) * 4;
#pragma unroll
      for (int q = 0; q < 4; ++q) {
        float v = acc[i][j][q];
        int grow = grow0 + q;
        if constexpr (MODE == 0) {
          if (gcol < DIN) {
            zb[(size_t)grow * DIN + gcol] = f2b(v);
          } else if (gcol < DIN + CONVD) {
            xbcb[(size_t)grow * CONVD + (gcol - DIN)] = f2b(v);
          } else if (gcol < DPROJ) {
            dtraw[(size_t)grow * HH + (gcol - DIN - CONVD)] = v;
          }
        } else {
          Cout[(size_t)grow * DM + gcol] = v;
        }
      }
    }
  }
}

// ---------------------------------------------------------------------------
// Depthwise causal conv1d (k=4) + bias + silu + splits; dt softplus; dtA.
// Fast-exp silu/softplus (error < bf16 rounding).
// ---------------------------------------------------------------------------
__global__ __launch_bounds__(256) void conv_act(
    const bf16* __restrict__ xbc, const float* __restrict__ dtraw,
    const float* __restrict__ convw, const float* __restrict__ convb,
    const float* __restrict__ dtb, const float* __restrict__ alog,
    bf16* __restrict__ xs, bf16* __restrict__ Bb, bf16* __restrict__ Cb,
    float* __restrict__ dtv, float* __restrict__ dtA) {
  const int row = blockIdx.x;
  const int l   = row & (LL - 1);
  const int t   = threadIdx.x;
  if (t < HH) {
    float raw = dtraw[(size_t)row * HH + t] + dtb[t];
    float dt  = (raw > 20.f) ? raw : log1pf(fexp(raw));
    dtv[(size_t)row * HH + t] = dt;
    dtA[(size_t)row * HH + t] = -fexp(alog[t]) * dt;
  }
  for (int ch = t * 8; ch < CONVD; ch += 2048) {
    float acc[8];
#pragma unroll
    for (int j = 0; j < 8; ++j) acc[j] = convb[ch + j];
#pragma unroll
    for (int k = 0; k < 4; ++k) {
      if (l - 3 + k >= 0) {
        uint4 v = *(const uint4*)&xbc[(size_t)(row - 3 + k) * CONVD + ch];
        const bf16* pv = (const bf16*)&v;
        const float* wp = &convw[k * CONVD + ch];
#pragma unroll
        for (int j = 0; j < 8; ++j) acc[j] += b2f(pv[j]) * wp[j];
      }
    }
    short8 sv;
#pragma unroll
    for (int j = 0; j < 8; ++j) {
      float s = acc[j] / (1.f + fexp(-acc[j])); // silu
      sv[j] = f2bs(s);
    }
    if (ch < DIN) {
      *(short8*)&xs[(size_t)row * DIN + ch] = sv;
    } else if (ch < DIN + NSD) {
      *(short8*)&Bb[(size_t)row * NSD + (ch - DIN)] = sv;
    } else {
      *(short8*)&Cb[(size_t)row * NSD + (ch - DIN - NSD)] = sv;
    }
  }
}

// ---------------------------------------------------------------------------
// G[b,c,l,s] = dot(C[l,:], B[s,:]) — MFMA. One block per (b,c).
// ---------------------------------------------------------------------------
__global__ __launch_bounds__(256) void gmat(const bf16* __restrict__ Bb,
                                            const bf16* __restrict__ Cb,
                                            float* __restrict__ G) {
  const int c = blockIdx.x, b = blockIdx.y;
  const int row0 = (b * NC + c) * CHK;
  __shared__ short Csh[64][136];
  __shared__ short Bsh[64][136];
  const int t = threadIdx.x;
  const int lane = t & 63, w = t >> 6;
#pragma unroll
  for (int i = 0; i < 4; ++i) {
    int f = t + i * 256;
    int rr = f >> 4, n0 = (f & 15) * 8;
    *(uint4*)&Csh[rr][n0] = *(const uint4*)&Cb[(size_t)(row0 + rr) * NSD + n0];
    *(uint4*)&Bsh[rr][n0] = *(const uint4*)&Bb[(size_t)(row0 + rr) * NSD + n0];
  }
  __syncthreads();
  f32x4 acc[4] = {};
  const int r = lane & 15, hi = lane >> 4;
#pragma unroll
  for (int kk = 0; kk < 4; ++kk) {
    short8 af = *(const short8*)&Csh[16 * w + r][kk * 32 + hi * 8];
#pragma unroll
    for (int j = 0; j < 4; ++j) {
      short8 bg = *(const short8*)&Bsh[16 * j + r][kk * 32 + hi * 8];
      acc[j] = __builtin_amdgcn_mfma_f32_16x16x32_bf16(af, bg, acc[j], 0, 0, 0);
    }
  }
#pragma unroll
  for (int j = 0; j < 4; ++j)
#pragma unroll
    for (int q = 0; q < 4; ++q) {
      int ll = 16 * w + hi * 4 + q, ss = 16 * j + r;
      G[((size_t)(b * NC + c) * CHK + ll) * CHK + ss] = acc[j][q];
    }
}

// ---------------------------------------------------------------------------
// Per (b,c,h): cumsum(dtA) via Kogge-Stone; Y_diag (MFMA) + D-term fused
// (xs reconstructed from LDS xds/dt — no global re-read); states (MFMA).
// Fast-exp decay staging.
// ---------------------------------------------------------------------------
__global__ __launch_bounds__(256) void ssd_chunk(
    const float* __restrict__ G, const bf16* __restrict__ xsp,
    const bf16* __restrict__ Bb, const float* __restrict__ dtv,
    const float* __restrict__ dtA, const float* __restrict__ Dp,
    bf16* __restrict__ y, bf16* __restrict__ states, float* __restrict__ cumA) {
  const int h = blockIdx.x, c = blockIdx.y, b = blockIdx.z;
  const int row0 = (b * NC + c) * CHK;
  __shared__ short GMb[64][72];
  __shared__ short xdsT[64][72];
  __shared__ short BdT[128][72];
  __shared__ float cA[CHK], dec[CHK], sdt[CHK], dodt[CHK];
  const int t = threadIdx.x;
  const int lane = t & 63, w = t >> 6;
  const float Dh = Dp[h];
  if (t < CHK) {
    float dtl = dtv[(size_t)(row0 + t) * HH + h];
    sdt[t]  = dtl;
    dodt[t] = Dh / fmaxf(dtl, 1e-30f);
    float v = dtA[(size_t)(row0 + t) * HH + h];
#pragma unroll
    for (int o = 1; o < 64; o <<= 1) {
      float u = __shfl_up(v, o, 64);
      if (t >= o) v += u;
    }
    cA[t] = v;
  }
  __syncthreads();
  if (t < CHK) {
    dec[t] = fexp(cA[CHK - 1] - cA[t]);
    cumA[((size_t)(b * HH + h) * NC + c) * CHK + t] = cA[t];
  }
#pragma unroll
  for (int i = 0; i < 2; ++i) {
    int f = t + i * 256;
    int ll = f >> 3, p0 = (f & 7) * 8;
    uint4 v = *(const uint4*)&xsp[(size_t)(row0 + ll) * DIN + h * PP + p0];
    const bf16* pv = (const bf16*)&v;
    float dtl = sdt[ll];
#pragma unroll
    for (int j = 0; j < 8; ++j) xdsT[p0 + j][ll] = f2bs(b2f(pv[j]) * dtl);
  }
#pragma unroll
  for (int i = 0; i < 4; ++i) {
    int f = t + i * 256;
    int ll = f >> 4, s0 = (f & 15) * 4;
    float4 g = *(const float4*)&G[((size_t)(b * NC + c) * CHK + ll) * CHK + s0];
    float ca = cA[ll];
    GMb[ll][s0 + 0] = f2bs((s0 + 0 <= ll) ? g.x * fexp(ca - cA[s0 + 0]) : 0.f);
    GMb[ll][s0 + 1] = f2bs((s0 + 1 <= ll) ? g.y * fexp(ca - cA[s0 + 1]) : 0.f);
    GMb[ll][s0 + 2] = f2bs((s0 + 2 <= ll) ? g.z * fexp(ca - cA[s0 + 2]) : 0.f);
    GMb[ll][s0 + 3] = f2bs((s0 + 3 <= ll) ? g.w * fexp(ca - cA[s0 + 3]) : 0.f);
  }
  __syncthreads();
#pragma unroll
  for (int i = 0; i < 4; ++i) {
    int f = t + i * 256;
    int ll = f >> 4, n0 = (f & 15) * 8;
    uint4 v = *(const uint4*)&Bb[(size_t)(row0 + ll) * NSD + n0];
    const bf16* pv = (const bf16*)&v;
    float dl = dec[ll];
#pragma unroll
    for (int j = 0; j < 8; ++j) BdT[n0 + j][ll] = f2bs(b2f(pv[j]) * dl);
  }
  __syncthreads();
  const int r = lane & 15, hi = lane >> 4;
  {
    f32x4 acc[4] = {};
#pragma unroll
    for (int kk = 0; kk < 2; ++kk) {
      short8 af = *(const short8*)&GMb[16 * w + r][kk * 32 + hi * 8];
#pragma unroll
      for (int j = 0; j < 4; ++j) {
        short8 bg = *(const short8*)&xdsT[16 * j + r][kk * 32 + hi * 8];
        acc[j] = __builtin_amdgcn_mfma_f32_16x16x32_bf16(af, bg, acc[j], 0, 0, 0);
      }
    }
#pragma unroll
    for (int j = 0; j < 4; ++j)
#pragma unroll
      for (int q = 0; q < 4; ++q) {
        int ll = 16 * w + hi * 4 + q, pp = 16 * j + r;
        size_t idx = (size_t)(row0 + ll) * DIN + h * PP + pp;
        float xv = b2f(*(const bf16*)&xdsT[pp][ll]);   // xds = xs*dt (LDS)
        y[idx] = f2b(acc[j][q] + xv * dodt[ll]);       // + xs*D
      }
  }
  {
    f32x4 acc[8] = {};
#pragma unroll
    for (int kk = 0; kk < 2; ++kk) {
      short8 af = *(const short8*)&xdsT[16 * w + r][kk * 32 + hi * 8];
#pragma unroll
      for (int j = 0; j < 8; ++j) {
        short8 bg = *(const short8*)&BdT[16 * j + r][kk * 32 + hi * 8];
        acc[j] = __builtin_amdgcn_mfma_f32_16x16x32_bf16(af, bg, acc[j], 0, 0, 0);
      }
    }
    size_t sb = ((size_t)(b * NC + c) * HH + h) * (PP * NSD);
#pragma unroll
    for (int j = 0; j < 8; ++j)
#pragma unroll
      for (int q = 0; q < 4; ++q) {
        int pp = 16 * w + hi * 4 + q, nn = 16 * j + r;
        states[sb + (size_t)pp * NSD + nn] = f2b(acc[j][q]);
      }
  }
}

// ---------------------------------------------------------------------------
// Inter-chunk sequential scan, in place (bf16 storage, fp32 carry).
// ---------------------------------------------------------------------------
__global__ __launch_bounds__(256) void scan(bf16* __restrict__ states,
                                            const float* __restrict__ cumA) {
  const int q = blockIdx.x, h = blockIdx.y, b = blockIdx.z;
  const int t = threadIdx.x;
  __shared__ float tots[NC];
  if (t < NC)
    tots[t] = fexp(cumA[((size_t)(b * HH + h) * NC + t) * CHK + CHK - 1]);
  __syncthreads();
  const int off = q * 2048 + t * 8;
  const size_t cstride = (size_t)HH * PP * NSD;
  size_t base = ((size_t)(b * NC) * HH + h) * (PP * NSD) + off;
  float S[8] = {};
  uint4 v0 = *(const uint4*)&states[base];
  uint4 v1 = *(const uint4*)&states[base + cstride];
  for (int c = 0; c < NC; ++c) {
    uint4 cv = v0;
    v0 = v1;
    if (c + 2 < NC) v1 = *(const uint4*)&states[base + 2 * cstride];
    float tot = tots[c];
    const bf16* pin = (const bf16*)&cv;
    short8 sv;
#pragma unroll
    for (int i = 0; i < 8; ++i) {
      float cs = b2f(pin[i]);
      sv[i] = f2bs(S[i]);
      S[i] = S[i] * tot + cs;
    }
    *(short8*)&states[base] = sv;
    base += cstride;
  }
}

// ---------------------------------------------------------------------------
// Y_off[l][p] = dot(C[l,:], S[p,:]) — MFMA; y += Y_off*exp(cA).
// ---------------------------------------------------------------------------
__global__ __launch_bounds__(256) void yoff(
    const bf16* __restrict__ Cb, const bf16* __restrict__ states,
    const float* __restrict__ cumA, bf16* __restrict__ y) {
  const int h = blockIdx.x, c = blockIdx.y, b = blockIdx.z;
  const int row0 = (b * NC + c) * CHK;
  __shared__ short Csh[64][136];
  __shared__ short Ssh[64][136];
  __shared__ float dcy[CHK];
  const int t = threadIdx.x;
  const int lane = t & 63, w = t >> 6;
  if (t < CHK) dcy[t] = fexp(cumA[((size_t)(b * HH + h) * NC + c) * CHK + t]);
  const size_t sbase = ((size_t)(b * NC + c) * HH + h) * (PP * NSD);
#pragma unroll
  for (int i = 0; i < 4; ++i) {
    int f = t + i * 256;
    int rr = f >> 4, n0 = (f & 15) * 8;
    *(uint4*)&Csh[rr][n0] = *(const uint4*)&Cb[(size_t)(row0 + rr) * NSD + n0];
    *(uint4*)&Ssh[rr][n0] = *(const uint4*)&states[sbase + (size_t)rr * NSD + n0];
  }
  __syncthreads();
  f32x4 acc[4] = {};
  const int r = lane & 15, hi = lane >> 4;
#pragma unroll
  for (int kk = 0; kk < 4; ++kk) {
    short8 af = *(const short8*)&Csh[16 * w + r][kk * 32 + hi * 8];
#pragma unroll
    for (int j = 0; j < 4; ++j) {
      short8 bg = *(const short8*)&Ssh[16 * j + r][kk * 32 + hi * 8];
      acc[j] = __builtin_amdgcn_mfma_f32_16x16x32_bf16(af, bg, acc[j], 0, 0, 0);
    }
  }
#pragma unroll
  for (int j = 0; j < 4; ++j)
#pragma unroll
    for (int q = 0; q < 4; ++q) {
      int ll = 16 * w + hi * 4 + q, pp = 16 * j + r;
      size_t idx = (size_t)(row0 + ll) * DIN + h * PP + pp;
      y[idx] = f2b(b2f(y[idx]) + acc[j][q] * dcy[ll]);
    }
}

// ---------------------------------------------------------------------------
// yz = y * silu(z); RMS-normalize over d_inner; scale; bf16 out. Vectorized.
// ---------------------------------------------------------------------------
__global__ __launch_bounds__(256) void gatenorm(const bf16* __restrict__ y,
                                                const bf16* __restrict__ zb,
                                                const float* __restrict__ nsc,
                                                bf16* __restrict__ outn) {
  const int row = blockIdx.x, t = threadIdx.x;
  const int ch = t * 8;
  uint4 yv4 = *(const uint4*)&y [(size_t)row * DIN + ch];
  uint4 zv4 = *(const uint4*)&zb[(size_t)row * DIN + ch];
  const bf16* yp = (const bf16*)&yv4;
  const bf16* zp = (const bf16*)&zv4;
  float v[8];
  float ss = 0.f;
#pragma unroll
  for (int i = 0; i < 8; ++i) {
    float z  = b2f(zp[i]);
    float g  = b2f(yp[i]) * z / (1.f + fexp(-z));
    v[i] = g;
    ss += g * g;
  }
#pragma unroll
  for (int off = 32; off > 0; off >>= 1) ss += __shfl_down(ss, off, 64);
  __shared__ float red[4];
  if ((t & 63) == 0) red[t >> 6] = ss;
  __syncthreads();
  float tot = red[0] + red[1] + red[2] + red[3];
  float r = rsqrtf(tot * (1.f / DIN) + 1e-6f);
  short8 o;
#pragma unroll
  for (int i = 0; i < 8; ++i) o[i] = f2bs(v[i] * r * nsc[ch + i]);
  *(short8*)&outn[(size_t)row * DIN + ch] = o;
}

// ---------------------------------------------------------------------------
extern "C" void kernel_launch(void* const* d_in, const int* in_sizes, int n_in,
                              void* d_out, int out_size, void* d_ws, size_t ws_size,
                              hipStream_t stream) {
  const float* x     = (const float*)d_in[0];
  const float* inw   = (const float*)d_in[1];
  const float* convw = (const float*)d_in[2];
  const float* convb = (const float*)d_in[3];
  const float* dtb   = (const float*)d_in[4];
  const float* alog  = (const float*)d_in[5];
  const float* Dp    = (const float*)d_in[6];
  const float* nsc   = (const float*)d_in[7];
  const float* outw  = (const float*)d_in[8];
  float* out = (float*)d_out;

  // workspace layout — ~209 MB total (bf16 intermediates, aliased reuse)
  char* p = (char*)d_ws;
  bf16*  zb     = (bf16*)p;  p += (size_t)ROWS * DIN * 2;          //  33.6 MB
  bf16*  xbcb   = (bf16*)p;  p += (size_t)ROWS * CONVD * 2;        //  37.7 MB
  bf16*  y      = xbcb;      // reuse: conv consumes xbcb before y is written
  float* dtraw  = (float*)p; p += (size_t)ROWS * HH * 4;           //   1.0 MB
  bf16*  xs     = (bf16*)p;  p += (size_t)ROWS * DIN * 2;          //  33.6 MB
  bf16*  states = (bf16*)p;  p += (size_t)BB * NC * HH * PP * NSD * 2; // 67.1 MB
  bf16*  normb  = states;    // reuse: yoff consumes states before norm written
  bf16*  Bb     = (bf16*)p;  p += (size_t)ROWS * NSD * 2;          //   2.1 MB
  bf16*  Cb     = (bf16*)p;  p += (size_t)ROWS * NSD * 2;          //   2.1 MB
  float* dtv    = (float*)p; p += (size_t)ROWS * HH * 4;           //   1.0 MB
  float* dtA    = (float*)p; p += (size_t)ROWS * HH * 4;           //   1.0 MB
  float* cumA   = (float*)p; p += (size_t)BB * HH * NC * CHK * 4;  //   1.0 MB
  float* G      = (float*)p; p += (size_t)BB * NC * CHK * CHK * 4; //   2.1 MB
  bf16*  xb     = (bf16*)p;  p += (size_t)ROWS * DM * 2;           //  16.8 MB
  bf16*  BtIn   = (bf16*)p;  p += (size_t)NPAD * DM * 2;           //   9.2 MB
  bf16*  BtOut  = xb;        // reuse: xb dead after in_proj GEMM

  // 0a. x -> bf16
  convert_bf16<<<(ROWS * DM / 4 + 255) / 256, 256, 0, stream>>>(x, xb, ROWS * DM / 4);
  // 0b. in_proj_w [DM][DPROJ] -> BtIn bf16 [NPAD][DM]
  transpose_w<<<dim3(NPAD / 32, DM / 32), 256, 0, stream>>>(inw, BtIn, DM, DPROJ);
  // 1. in_proj GEMM (MFMA 128x128, single-barrier pipeline, split outputs)
  gemm_mfma<0, 4><<<dim3(NPAD / 128, ROWS / 128), 256, 0, stream>>>(
      (const short*)xb, (const short*)BtIn, DM, zb, xbcb, dtraw, nullptr);
  // 0c. out_proj_w [DIN][DM] -> BtOut bf16 [DM][DIN]  (into dead xb region)
  transpose_w<<<dim3(DM / 32, DIN / 32), 256, 0, stream>>>(outw, BtOut, DIN, DM);
  // 2. conv + activations + splits (bf16 B/C)
  conv_act<<<ROWS, 256, 0, stream>>>(xbcb, dtraw, convw, convb, dtb, alog,
                                     xs, Bb, Cb, dtv, dtA);
  // 3. G = C B^T per chunk (MFMA)
  gmat<<<dim3(NC, BB), 256, 0, stream>>>(Bb, Cb, G);
  // 4. Y_diag + D-term + chunk states per (b,c,h) (MFMA)
  ssd_chunk<<<dim3(HH, NC, BB), 256, 0, stream>>>(G, xs, Bb, dtv, dtA, Dp,
                                                  y, states, cumA);
  // 5. inter-chunk scan (in place, 2-deep prefetch)
  scan<<<dim3(4, HH, BB), 256, 0, stream>>>(states, cumA);
  // 6. Y_off (MFMA; D-term already applied)
  yoff<<<dim3(HH, NC, BB), 256, 0, stream>>>(Cb, states, cumA, y);
  // 7. gate + RMSNorm (normed overwrites states region)
  gatenorm<<<ROWS, 256, 0, stream>>>(y, zb, nsc, normb);
  // 8. out_proj GEMM (MFMA 128x128, single-barrier pipeline, fp32 out)
  gemm_mfma<1, 4><<<dim3(DM / 128, ROWS / 128), 256, 0, stream>>>(
      (const short*)normb, (const short*)BtOut, DIN, nullptr, nullptr, nullptr, out);

  (void)in_sizes; (void)n_in; (void)out_size; (void)ws_size;
}